// Round 5
// baseline (4271.199 us; speedup 1.0000x reference)
//
#include <hip/hip_runtime.h>

#define NB 4
#define NPER 8192
#define MPER 2048
#define KNN 16
#define CIN 64
#define CO 128
#define MTOT (NB*MPER)

typedef unsigned long long u64;
typedef unsigned int u32;

__device__ __forceinline__ float med3f(float a, float b, float c) {
    return __builtin_amdgcn_fmed3f(a, b, c);
}

// ---------------- init: zero stats + write row_splits ----------------
__global__ void k_init(float* __restrict__ stats, float* __restrict__ rs) {
    int t = threadIdx.x;
    if (t < 256) stats[t] = 0.f;
    if (t < 5) rs[t] = (float)(t * MPER);
}

// DPP compare-select step on a packed u64 key (max).
#define DPPSTEP(key, CTRL, RM) do {                                                   \
    unsigned lo_ = (unsigned)(key), hi_ = (unsigned)((key) >> 32);                    \
    unsigned nlo = (unsigned)__builtin_amdgcn_update_dpp((int)lo_, (int)lo_, CTRL, RM, 0xf, false); \
    unsigned nhi = (unsigned)__builtin_amdgcn_update_dpp((int)hi_, (int)hi_, CTRL, RM, 0xf, false); \
    unsigned long long ok_ = ((unsigned long long)nhi << 32) | nlo;                   \
    if (ok_ > (key)) (key) = ok_;                                                     \
} while (0)

#define DPP6(key) do { \
    DPPSTEP(key, 0xB1,  0xF); \
    DPPSTEP(key, 0x4E,  0xF); \
    DPPSTEP(key, 0x141, 0xF); \
    DPPSTEP(key, 0x140, 0xF); \
    DPPSTEP(key, 0x142, 0xA); \
    DPPSTEP(key, 0x143, 0xC); \
} while (0)

// ---------------- FPS: Morton-bucketed brute force with per-thread skip bound ----
// One block per batch, 512 threads, 16 sorted pts/thread.
__launch_bounds__(512, 1)
__global__ void k_fps(const float* __restrict__ pts, float* __restrict__ out_np,
                      float4* __restrict__ qpts) {
    #pragma clang fp contract(off)
    __shared__ __align__(16) char smraw[NPER * 16];   // union: sort keys, then point table
    __shared__ u64 red[2][8];
    __shared__ float gb[8][6];
    __shared__ int slot0sh;
    u32*    sdu = (u32*)smraw;
    float4* spt = (float4*)smraw;

    const int b = blockIdx.x;
    const int t = threadIdx.x;
    const int ibase = t * 16;
    const float* pb = pts + (size_t)b * NPER * 3;
    const float4* pb4 = (const float4*)pb;

    // --- load my 16 original-order points into regs ---
    float f[48];
    #pragma unroll
    for (int j = 0; j < 12; ++j) {
        float4 v = pb4[t * 12 + j];
        f[j*4+0] = v.x; f[j*4+1] = v.y; f[j*4+2] = v.z; f[j*4+3] = v.w;
    }
    float px[16], py[16], pz[16], dd[16];
    int or16[16];
    #pragma unroll
    for (int s = 0; s < 16; ++s) { px[s] = f[3*s]; py[s] = f[3*s+1]; pz[s] = f[3*s+2]; }

    // --- global bbox (block reduce) ---
    float mnx=1e30f,mny=1e30f,mnz=1e30f,mxx=-1e30f,mxy=-1e30f,mxz=-1e30f;
    #pragma unroll
    for (int s = 0; s < 16; ++s) {
        mnx=fminf(mnx,px[s]); mxx=fmaxf(mxx,px[s]);
        mny=fminf(mny,py[s]); mxy=fmaxf(mxy,py[s]);
        mnz=fminf(mnz,pz[s]); mxz=fmaxf(mxz,pz[s]);
    }
    #pragma unroll
    for (int off=1; off<64; off<<=1) {
        mnx=fminf(mnx,__shfl_xor(mnx,off)); mxx=fmaxf(mxx,__shfl_xor(mxx,off));
        mny=fminf(mny,__shfl_xor(mny,off)); mxy=fmaxf(mxy,__shfl_xor(mxy,off));
        mnz=fminf(mnz,__shfl_xor(mnz,off)); mxz=fmaxf(mxz,__shfl_xor(mxz,off));
    }
    if ((t&63)==0) {
        int w = t>>6;
        gb[w][0]=mnx; gb[w][1]=mny; gb[w][2]=mnz; gb[w][3]=mxx; gb[w][4]=mxy; gb[w][5]=mxz;
    }
    __syncthreads();
    mnx=1e30f; mny=1e30f; mnz=1e30f; mxx=-1e30f; mxy=-1e30f; mxz=-1e30f;
    #pragma unroll
    for (int w = 0; w < 8; ++w) {
        mnx=fminf(mnx,gb[w][0]); mny=fminf(mny,gb[w][1]); mnz=fminf(mnz,gb[w][2]);
        mxx=fmaxf(mxx,gb[w][3]); mxy=fmaxf(mxy,gb[w][4]); mxz=fmaxf(mxz,gb[w][5]);
    }
    float scx = 63.0f / fmaxf(mxx-mnx, 1e-20f);
    float scy = 63.0f / fmaxf(mxy-mny, 1e-20f);
    float scz = 63.0f / fmaxf(mxz-mnz, 1e-20f);

    // --- morton keys for my 16 points ---
    #pragma unroll
    for (int s = 0; s < 16; ++s) {
        u32 qx = (u32)min(63, max(0, (int)((px[s]-mnx)*scx)));
        u32 qy = (u32)min(63, max(0, (int)((py[s]-mny)*scy)));
        u32 qz = (u32)min(63, max(0, (int)((pz[s]-mnz)*scz)));
        u32 mx_=qx, my_=qy, mz_=qz;
        #define P1B2(v) do { v=(v|(v<<8))&0x0300F00Fu; v=(v|(v<<4))&0x030C30C3u; v=(v|(v<<2))&0x09249249u; } while(0)
        P1B2(mx_); P1B2(my_); P1B2(mz_);
        u32 m = (mx_<<2)|(my_<<1)|mz_;
        sdu[ibase + s] = (m << 13) | (u32)(ibase + s);
    }
    __syncthreads();

    // --- bitonic sort ascending on sdu (proven in R3) ---
    for (u32 kk2 = 2; kk2 <= NPER; kk2 <<= 1) {
        for (u32 j = kk2 >> 1; j > 0; j >>= 1) {
            for (int ii = t; ii < NPER; ii += 512) {
                int l = ii ^ (int)j;
                if (l > ii) {
                    u32 a = sdu[ii], bb = sdu[l];
                    bool asc = ((ii & (int)kk2) == 0);
                    if ((a > bb) == asc) { sdu[ii] = bb; sdu[l] = a; }
                }
            }
            __syncthreads();
        }
    }

    // --- read my sorted keys, then overwrite union with point table ---
    u32 kreg[16];
    #pragma unroll
    for (int s = 0; s < 16; ++s) kreg[s] = sdu[ibase + s];
    __syncthreads();

    float bx0=1e30f,by0=1e30f,bz0=1e30f,bx1=-1e30f,by1=-1e30f,bz1=-1e30f;
    #pragma unroll
    for (int s = 0; s < 16; ++s) {
        int orig = (int)(kreg[s] & 0x1FFFu);
        float x = pb[orig*3], y = pb[orig*3+1], z = pb[orig*3+2];
        px[s]=x; py[s]=y; pz[s]=z; or16[s]=orig; dd[s]=1e10f;
        spt[ibase + s] = make_float4(x, y, z, 0.f);
        if (orig == 0) slot0sh = ibase + s;
        bx0=fminf(bx0,x); bx1=fmaxf(bx1,x);
        by0=fminf(by0,y); by1=fmaxf(by1,y);
        bz0=fminf(bz0,z); bz1=fmaxf(bz1,z);
    }
    __syncthreads();

    float4 c0 = spt[slot0sh];
    float cx = c0.x, cy = c0.y, cz = c0.z;
    if (t == 0) {
        size_t row = (size_t)b * MPER;
        out_np[row*3+0]=cx; out_np[row*3+1]=cy; out_np[row*3+2]=cz;
        qpts[row] = make_float4(cx, cy, cz, 0.f);
    }

    float bv = 1e10f;          // local max of dd (any value < 1e10 forces first update)
    u64 key = 0;               // cached packed key; valid after first update (i=1 always updates)

    for (int i = 1; i < MPER; ++i) {
        // bound check: can this thread's 16 slots possibly change?
        float ex = fmaxf(fmaxf(bx0 - cx, cx - bx1), 0.f);
        float ey = fmaxf(fmaxf(by0 - cy, cy - by1), 0.f);
        float ez = fmaxf(fmaxf(bz0 - cz, cz - bz1), 0.f);
        float lb = fmaf(ex, ex, fmaf(ey, ey, ez * ez));
        if (!(lb > bv * 1.001f)) {
            // full exact update (reference arithmetic) + local argmax w/ orig tie-break
            float nbv = -1.f; int nbo = 0x7FFFFFFF; int nbs = 0;
            #pragma unroll
            for (int s = 0; s < 16; ++s) {
                float dx = px[s]-cx, dy = py[s]-cy, dz = pz[s]-cz;
                float t0 = dx*dx, t1 = dy*dy, t2 = dz*dz;
                float d = (t0 + t1) + t2;
                float nd = fminf(dd[s], d);
                dd[s] = nd;
                bool bet = (nd > nbv) || ((nd == nbv) && (or16[s] < nbo));
                nbv = bet ? nd : nbv;
                nbo = bet ? or16[s] : nbo;
                nbs = bet ? s : nbs;
            }
            bv = nbv;
            key = ((u64)__float_as_uint(nbv) << 26)
                | ((u64)((~(u32)nbo) & 0x1FFFu) << 13)
                | (u32)(ibase + nbs);
        }

        u64 rk = key;
        DPP6(rk);   // 64-lane max in lane 63

        if ((t & 63) == 63) red[i & 1][t >> 6] = rk;
        __syncthreads();            // single barrier; parity buffer avoids WAW

        const int p = i & 1;
        u64 k0 = red[p][0], k1 = red[p][1], k2 = red[p][2], k3 = red[p][3];
        u64 k4 = red[p][4], k5 = red[p][5], k6 = red[p][6], k7 = red[p][7];
        u64 a0 = k0 > k1 ? k0 : k1, a1 = k2 > k3 ? k2 : k3;
        u64 a2 = k4 > k5 ? k4 : k5, a3 = k6 > k7 ? k6 : k7;
        u64 b0 = a0 > a1 ? a0 : a1, b1 = a2 > a3 ? a2 : a3;
        u64 kbest = b0 > b1 ? b0 : b1;
        const int wslot = (int)(kbest & 0x1FFFu);

        float4 c = spt[wslot];
        cx = c.x; cy = c.y; cz = c.z;

        if (t == 0) {
            size_t row = (size_t)b * MPER + i;
            out_np[row*3+0] = cx; out_np[row*3+1] = cy; out_np[row*3+2] = cz;
            qpts[row] = make_float4(cx, cy, cz, 0.f);
        }
    }
}

// ---------------- KNN: 64 queries/block, 4 lanes/query ----------------
#define CCAP 28
__launch_bounds__(256, 1)
__global__ void k_knn(const float* __restrict__ pts, const float4* __restrict__ qpts,
                      int* __restrict__ nidx) {
    #pragma clang fp contract(off)
    __shared__ float4 sp[2][4][514];     // [buf][quarter][pt], padded for banks
    __shared__ float  ndl[256][16];
    __shared__ u32    candl[256][CCAP];
    __shared__ int    ccnt[256], ccless[256];
    __shared__ float  taub[64];

    const int t = threadIdx.x;
    const int qloc = t >> 2, sub = t & 3;
    const int q = blockIdx.x * 64 + qloc;
    const int b = q >> 11;
    const float4 qp = qpts[q];
    const float qq = (qp.x * qp.x + qp.y * qp.y) + qp.z * qp.z;
    const float* pb = pts + (size_t)b * NPER * 3;
    const int wq = t >> 6, wl = t & 63;   // staging: wave wq fills quarter wq

    float4 L[6];   // prefetched chunk: my 8 points (24 floats)
    #define LOADC(c) do { const float4* src_ = (const float4*)(pb + (size_t)(c) * 2048 * 3); \
        _Pragma("unroll") for (int u_ = 0; u_ < 6; ++u_) L[u_] = src_[t * 6 + u_]; } while (0)
    #define WRITEC(pbuf) do { \
        float fl_[24]; \
        _Pragma("unroll") for (int u_ = 0; u_ < 6; ++u_) { \
            fl_[u_*4+0]=L[u_].x; fl_[u_*4+1]=L[u_].y; fl_[u_*4+2]=L[u_].z; fl_[u_*4+3]=L[u_].w; } \
        _Pragma("unroll") for (int r_ = 0; r_ < 8; ++r_) { \
            float x_=fl_[3*r_], y_=fl_[3*r_+1], z_=fl_[3*r_+2]; \
            float pp_=(x_*x_ + y_*y_) + z_*z_; \
            sp[pbuf][wq][wl*8 + r_] = make_float4(x_,y_,z_,pp_); } } while (0)

    // ---- pass 1: per-lane sorted top-16 distances over my 2048-pt stream ----
    float nd[16];
    #pragma unroll
    for (int j = 0; j < 16; ++j) nd[j] = 1e30f;

    LOADC(0); WRITEC(0); LOADC(1);
    __syncthreads();
    for (int c = 0; c < 4; ++c) {
        const int pbuf = c & 1;
        #pragma unroll 4
        for (int j = 0; j < 512; ++j) {
            float4 p = sp[pbuf][sub][j];
            float dot = (qp.x * p.x + qp.y * p.y) + qp.z * p.z;
            float d = (qq + p.w) - 2.f * dot;
            if (d < nd[15]) {
                #pragma unroll
                for (int u = 15; u >= 1; --u) nd[u] = med3f(d, nd[u-1], nd[u]);
                nd[0] = fminf(nd[0], d);
            }
        }
        __syncthreads();
        if (c < 3) {
            WRITEC((c + 1) & 1);
            if (c < 2) LOADC(c + 2);
            __syncthreads();
        }
    }
    #pragma unroll
    for (int j = 0; j < 16; ++j) ndl[t][j] = nd[j];
    __syncthreads();

    // leader: exact 16th-smallest via 4-way merge of sorted lists
    if (sub == 0) {
        int p0=0,p1=0,p2=0,p3=0;
        float c0=ndl[t][0], c1=ndl[t+1][0], c2=ndl[t+2][0], c3=ndl[t+3][0];
        float tau = 0.f;
        for (int it = 0; it < 16; ++it) {
            if (c0 <= c1 && c0 <= c2 && c0 <= c3) { tau=c0; ++p0; c0 = (p0<16)?ndl[t][p0]:1e30f; }
            else if (c1 <= c2 && c1 <= c3)        { tau=c1; ++p1; c1 = (p1<16)?ndl[t+1][p1]:1e30f; }
            else if (c2 <= c3)                    { tau=c2; ++p2; c2 = (p2<16)?ndl[t+2][p2]:1e30f; }
            else                                  { tau=c3; ++p3; c3 = (p3<16)?ndl[t+3][p3]:1e30f; }
        }
        taub[qloc] = tau;
    }
    __syncthreads();
    const float tau = taub[qloc];

    // ---- pass 2: collect indices with d <= tau (bit-identical recompute) ----
    int cnt = 0, cless = 0;
    LOADC(0); WRITEC(0); LOADC(1);
    __syncthreads();
    for (int c = 0; c < 4; ++c) {
        const int pbuf = c & 1;
        for (int j = 0; j < 512; ++j) {
            float4 p = sp[pbuf][sub][j];
            float dot = (qp.x * p.x + qp.y * p.y) + qp.z * p.z;
            float d = (qq + p.w) - 2.f * dot;
            if (d <= tau && cnt < CCAP) {
                bool eq = !(d < tau);
                candl[t][cnt++] = (u32)(c * 2048 + sub * 512 + j) | (eq ? 0x80000000u : 0u);
                if (!eq) cless++;
            }
        }
        __syncthreads();
        if (c < 3) {
            WRITEC((c + 1) & 1);
            if (c < 2) LOADC(c + 2);
            __syncthreads();
        }
    }
    ccnt[t] = cnt; ccless[t] = cless;
    __syncthreads();

    // leader: merge 4 candidate streams in ascending point-index order; quota select
    if (sub == 0) {
        int n0=ccnt[t], n1=ccnt[t+1], n2=ccnt[t+2], n3=ccnt[t+3];
        int quota = 16 - (ccless[t]+ccless[t+1]+ccless[t+2]+ccless[t+3]);
        int p0=0,p1=0,p2=0,p3=0, kept=0, eq_used=0;
        u32 h0 = n0 ? candl[t][0]   : 0xFFFFFFFFu;
        u32 h1 = n1 ? candl[t+1][0] : 0xFFFFFFFFu;
        u32 h2 = n2 ? candl[t+2][0] : 0xFFFFFFFFu;
        u32 h3 = n3 ? candl[t+3][0] : 0xFFFFFFFFu;
        size_t obase = (size_t)q * KNN;
        for (int g = 0; g < 4*CCAP && kept < 16; ++g) {
            u32 m0 = h0 & 0x7fffffffu, m1 = h1 & 0x7fffffffu;
            u32 m2 = h2 & 0x7fffffffu, m3 = h3 & 0x7fffffffu;
            u32 v;
            if (m0 <= m1 && m0 <= m2 && m0 <= m3) { v=h0; ++p0; h0 = (p0<n0)?candl[t][p0]:0xFFFFFFFFu; }
            else if (m1 <= m2 && m1 <= m3)        { v=h1; ++p1; h1 = (p1<n1)?candl[t+1][p1]:0xFFFFFFFFu; }
            else if (m2 <= m3)                    { v=h2; ++p2; h2 = (p2<n2)?candl[t+2][p2]:0xFFFFFFFFu; }
            else                                  { v=h3; ++p3; h3 = (p3<n3)?candl[t+3][p3]:0xFFFFFFFFu; }
            if (v == 0xFFFFFFFFu) break;
            bool eq = (v >> 31) != 0;
            bool take = !eq || (eq_used < quota);
            if (take) {
                if (eq) ++eq_used;
                nidx[obase + kept] = b * NPER + (int)(v & 0x7fffffffu);
                ++kept;
            }
        }
    }
    #undef LOADC
    #undef WRITEC
}

// ---------------- fused gather + linear + stats + k-minmax ----------------
__launch_bounds__(128, 4)
__global__ void k_stats(const float* __restrict__ pts, const float* __restrict__ feat,
                        const float* __restrict__ W, const int* __restrict__ nidx,
                        const float4* __restrict__ qpts, float* __restrict__ ymax,
                        float* __restrict__ ymin, float* __restrict__ stats) {
    __shared__ float4 g4[KNN][17];
    const int t = threadIdx.x;
    float w[68];
    const float* wr = W + t * 67;
    #pragma unroll
    for (int c = 0; c < 64; ++c) w[c] = wr[3 + c];
    w[64] = wr[0]; w[65] = wr[1]; w[66] = wr[2]; w[67] = 0.f;

    float s_sum = 0.f, s_sq = 0.f;
    const int k0 = t >> 3, p8 = t & 7;
    for (int mi = 0; mi < 8; ++mi) {
        const int m0 = blockIdx.x * 8 + mi;
        {
            int nid = nidx[(size_t)m0 * KNN + k0];
            const float4* fr = (const float4*)(feat + (size_t)nid * CIN);
            g4[k0][p8*2]   = fr[p8*2];
            g4[k0][p8*2+1] = fr[p8*2+1];
        }
        if (t < 16) {
            int nid = nidx[(size_t)m0 * KNN + t];
            float4 qp = qpts[m0];
            float x = pts[(size_t)nid*3], y = pts[(size_t)nid*3+1], z = pts[(size_t)nid*3+2];
            g4[t][16] = make_float4(x - qp.x, y - qp.y, z - qp.z, 0.f);
        }
        __syncthreads();
        float vmax = -1e30f, vmin = 1e30f;
        #pragma unroll 1
        for (int k = 0; k < KNN; ++k) {
            float y0 = 0.f, y1 = 0.f, y2 = 0.f, y3 = 0.f;
            #pragma unroll
            for (int c4 = 0; c4 < 17; ++c4) {
                float4 gv = g4[k][c4];
                y0 = fmaf(gv.x, w[c4*4+0], y0);
                y1 = fmaf(gv.y, w[c4*4+1], y1);
                y2 = fmaf(gv.z, w[c4*4+2], y2);
                y3 = fmaf(gv.w, w[c4*4+3], y3);
            }
            float y = (y0 + y1) + (y2 + y3);
            vmax = fmaxf(vmax, y); vmin = fminf(vmin, y);
            s_sum += y; s_sq = fmaf(y, y, s_sq);
        }
        ymax[(size_t)m0 * CO + t] = vmax;
        ymin[(size_t)m0 * CO + t] = vmin;
        __syncthreads();
    }
    atomicAdd(stats + t, s_sum);
    atomicAdd(stats + CO + t, s_sq);
}

// ---------------- finalize BN scale/shift ----------------
__global__ void k_final(const float* __restrict__ stats, const float* __restrict__ gamma,
                        const float* __restrict__ beta, float* __restrict__ sb) {
    int o = threadIdx.x;
    const float inv = 1.f / (float)(MTOT * KNN);
    float mean = stats[o] * inv;
    float var = stats[CO + o] * inv - mean * mean;
    var = fmaxf(var, 0.f);
    float s = gamma[o] * rsqrtf(var + 1e-5f);
    sb[o] = s;
    sb[CO + o] = beta[o] - mean * s;
}

// ---------------- epilogue: relu(s*ext + b) ----------------
__global__ void k_out(const float* __restrict__ ymax, const float* __restrict__ ymin,
                      const float* __restrict__ sb, float* __restrict__ out_feat) {
    int tid = blockIdx.x * 256 + threadIdx.x;
    int o = tid & (CO - 1);
    float s = sb[o], bb = sb[CO + o];
    float yv = (s >= 0.f) ? ymax[tid] : ymin[tid];
    out_feat[tid] = fmaxf(fmaf(s, yv, bb), 0.f);
}

extern "C" void kernel_launch(void* const* d_in, const int* in_sizes, int n_in,
                              void* d_out, int out_size, void* d_ws, size_t ws_size,
                              hipStream_t stream) {
    const float* pts   = (const float*)d_in[0];
    const float* feat  = (const float*)d_in[1];
    const float* W     = (const float*)d_in[3];
    const float* gamma = (const float*)d_in[4];
    const float* beta  = (const float*)d_in[5];
    float* out = (float*)d_out;
    char* ws = (char*)d_ws;

    float4* qpts = (float4*)(ws);                       // 131072 B
    int*    nidx = (int*)(ws + 131072);                 // 524288 B
    float*  stats = (float*)(ws + 655360);              // 1024 B
    float*  sb    = (float*)(ws + 656384);              // 1024 B
    float*  ymax  = (float*)(ws + 657408);              // 4 MB
    float*  ymin  = (float*)(ws + 657408 + 4194304);    // 4 MB

    float* out_np   = out;                    // (8192,3)
    float* out_feat = out + 24576;            // (8192,128)
    float* out_rs   = out + 24576 + 1048576;  // (5,)

    hipLaunchKernelGGL(k_init,  dim3(1), dim3(256), 0, stream, stats, out_rs);
    hipLaunchKernelGGL(k_fps,   dim3(NB), dim3(512), 0, stream, pts, out_np, qpts);
    hipLaunchKernelGGL(k_knn,   dim3(MTOT / 64), dim3(256), 0, stream, pts, qpts, nidx);
    hipLaunchKernelGGL(k_stats, dim3(MTOT / 8), dim3(128), 0, stream,
                       pts, feat, W, nidx, qpts, ymax, ymin, stats);
    hipLaunchKernelGGL(k_final, dim3(1), dim3(128), 0, stream, stats, gamma, beta, sb);
    hipLaunchKernelGGL(k_out,   dim3(MTOT * CO / 256), dim3(256), 0, stream,
                       ymax, ymin, sb, out_feat);
}

// Round 6
// 2473.858 us; speedup vs baseline: 1.7265x; 1.7265x over previous
//
#include <hip/hip_runtime.h>

#define NB 4
#define NPER 8192
#define MPER 2048
#define KNN 16
#define CIN 64
#define CO 128
#define MTOT (NB*MPER)

typedef unsigned long long u64;
typedef unsigned int u32;

__device__ __forceinline__ float med3f(float a, float b, float c) {
    return __builtin_amdgcn_fmed3f(a, b, c);
}

// ---------------- init: zero stats + write row_splits ----------------
__global__ void k_init(float* __restrict__ stats, float* __restrict__ rs) {
    int t = threadIdx.x;
    if (t < 256) stats[t] = 0.f;
    if (t < 5) rs[t] = (float)(t * MPER);
}

// f32 DPP max step: masked-out rows keep old value (bound_ctrl=false)
#define DPPFMAX(v, CTRL, RM) do {                                                     \
    float o_ = __uint_as_float((unsigned)__builtin_amdgcn_update_dpp(                 \
        (int)__float_as_uint(v), (int)__float_as_uint(v), CTRL, RM, 0xf, false));     \
    (v) = fmaxf((v), o_);                                                             \
} while (0)

// ---------------- FPS: one block per batch, 512 threads, 16 pts/lane ----------------
__launch_bounds__(512, 2)
__global__ void k_fps(const float* __restrict__ pts, float* __restrict__ out_np,
                      float4* __restrict__ qpts) {
    #pragma clang fp contract(off)
    __shared__ float4 spt[NPER];                 // 128 KiB point table (x,y,z,0)
    __shared__ u64 red[2][8];                    // parity-double-buffered wave partials
    const int b = blockIdx.x;
    const int t = threadIdx.x;
    const float4* pb4 = (const float4*)(pts + (size_t)b * NPER * 3);

    // load my 16 points (48 floats = 12 float4) straight into registers
    float f[48];
    #pragma unroll
    for (int j = 0; j < 12; ++j) {
        float4 v = pb4[t * 12 + j];
        f[j*4+0] = v.x; f[j*4+1] = v.y; f[j*4+2] = v.z; f[j*4+3] = v.w;
    }
    float px[16], py[16], pz[16], dd[16];
    #pragma unroll
    for (int s = 0; s < 16; ++s) {
        px[s] = f[3*s]; py[s] = f[3*s+1]; pz[s] = f[3*s+2];
        dd[s] = 1e10f;
        spt[t * 16 + s] = make_float4(px[s], py[s], pz[s], 0.f);
    }
    if (t == 0) {
        size_t row = (size_t)b * MPER;
        out_np[row*3+0] = px[0]; out_np[row*3+1] = py[0]; out_np[row*3+2] = pz[0];
        qpts[row] = make_float4(px[0], py[0], pz[0], 0.f);
    }
    __syncthreads();

    float4 c0 = spt[0];
    float cx = c0.x, cy = c0.y, cz = c0.z;
    const int lane = t & 63, wv = t >> 6;
    const int ibase = t * 16;

    for (int i = 1; i < MPER; ++i) {
        // local argmax over my 16 slots: two independent 8-deep chains (exact ref
        // arithmetic; strict > within each chain keeps lowest slot of that chain)
        float bvA = -1.f, bvB = -1.f;
        int bsA = 0, bsB = 1;
        #pragma unroll
        for (int s = 0; s < 16; s += 2) {
            {
                float dx = px[s] - cx, dy = py[s] - cy, dz = pz[s] - cz;
                float t0 = dx * dx, t1 = dy * dy, t2 = dz * dz;
                float d = (t0 + t1) + t2;
                float nd = fminf(dd[s], d);
                dd[s] = nd;
                bool bet = nd > bvA;
                bvA = bet ? nd : bvA;
                bsA = bet ? s : bsA;
            }
            {
                float dx = px[s+1] - cx, dy = py[s+1] - cy, dz = pz[s+1] - cz;
                float t0 = dx * dx, t1 = dy * dy, t2 = dz * dz;
                float d = (t0 + t1) + t2;
                float nd = fminf(dd[s+1], d);
                dd[s+1] = nd;
                bool bet = nd > bvB;
                bvB = bet ? nd : bvB;
                bsB = bet ? (s+1) : bsB;
            }
        }
        // exact merge: on tie, lower slot wins
        bool tb = (bvB > bvA) || ((bvB == bvA) && (bsB < bsA));
        float bv = tb ? bvB : bvA;
        int gidx = ibase + (tb ? bsB : bsA);

        // wave reduce on f32 (max lands in lane 63)
        float rv = bv;
        DPPFMAX(rv, 0xB1,  0xF);   // quad_perm xor1
        DPPFMAX(rv, 0x4E,  0xF);   // quad_perm xor2
        DPPFMAX(rv, 0x141, 0xF);   // row_half_mirror
        DPPFMAX(rv, 0x140, 0xF);   // row_mirror
        DPPFMAX(rv, 0x142, 0xA);   // row_bcast15 -> rows 1,3
        DPPFMAX(rv, 0x143, 0xC);   // row_bcast31 -> rows 2,3
        u32 wmu = (u32)__builtin_amdgcn_readlane((int)__float_as_uint(rv), 63);
        float wm = __uint_as_float(wmu);
        // fmax returns one of its inputs bitwise -> equality finds the tied lanes;
        // lanes ascend with global index, so lowest set lane = lowest index.
        u64 bal = __ballot(bv == wm);
        int wl = __ffsll((long long)bal) - 1;
        u32 sidx = (u32)__builtin_amdgcn_readlane(gidx, wl);

        if (lane == 0) red[i & 1][wv] = ((u64)wmu << 32) | (u32)~sidx;
        __syncthreads();            // single barrier; parity buffer avoids WAW

        const int p = i & 1;
        u64 k0 = red[p][0], k1 = red[p][1], k2 = red[p][2], k3 = red[p][3];
        u64 k4 = red[p][4], k5 = red[p][5], k6 = red[p][6], k7 = red[p][7];
        u64 a0 = k0 > k1 ? k0 : k1, a1 = k2 > k3 ? k2 : k3;
        u64 a2 = k4 > k5 ? k4 : k5, a3 = k6 > k7 ? k6 : k7;
        u64 b0 = a0 > a1 ? a0 : a1, b1 = a2 > a3 ? a2 : a3;
        u64 kbest = b0 > b1 ? b0 : b1;
        const int wslot = (int)(~(u32)kbest) & 0x1FFF;

        float4 c = spt[wslot];
        cx = c.x; cy = c.y; cz = c.z;

        if (t == 0) {
            size_t row = (size_t)b * MPER + i;
            out_np[row*3+0] = cx; out_np[row*3+1] = cy; out_np[row*3+2] = cz;
            qpts[row] = make_float4(cx, cy, cz, 0.f);
        }
    }
}

// ---------------- KNN: 64 queries/block, 4 lanes/query ----------------
#define CCAP 28
__launch_bounds__(256, 1)
__global__ void k_knn(const float* __restrict__ pts, const float4* __restrict__ qpts,
                      int* __restrict__ nidx) {
    #pragma clang fp contract(off)
    __shared__ float4 sp[2][4][514];     // [buf][quarter][pt], padded for banks
    __shared__ float  ndl[256][16];
    __shared__ u32    candl[256][CCAP];
    __shared__ int    ccnt[256], ccless[256];
    __shared__ float  taub[64];

    const int t = threadIdx.x;
    const int qloc = t >> 2, sub = t & 3;
    const int q = blockIdx.x * 64 + qloc;
    const int b = q >> 11;
    const float4 qp = qpts[q];
    const float qq = (qp.x * qp.x + qp.y * qp.y) + qp.z * qp.z;
    const float* pb = pts + (size_t)b * NPER * 3;
    const int wq = t >> 6, wl = t & 63;   // staging: wave wq fills quarter wq

    float4 L[6];   // prefetched chunk: my 8 points (24 floats)
    #define LOADC(c) do { const float4* src_ = (const float4*)(pb + (size_t)(c) * 2048 * 3); \
        _Pragma("unroll") for (int u_ = 0; u_ < 6; ++u_) L[u_] = src_[t * 6 + u_]; } while (0)
    #define WRITEC(pbuf) do { \
        float fl_[24]; \
        _Pragma("unroll") for (int u_ = 0; u_ < 6; ++u_) { \
            fl_[u_*4+0]=L[u_].x; fl_[u_*4+1]=L[u_].y; fl_[u_*4+2]=L[u_].z; fl_[u_*4+3]=L[u_].w; } \
        _Pragma("unroll") for (int r_ = 0; r_ < 8; ++r_) { \
            float x_=fl_[3*r_], y_=fl_[3*r_+1], z_=fl_[3*r_+2]; \
            float pp_=(x_*x_ + y_*y_) + z_*z_; \
            sp[pbuf][wq][wl*8 + r_] = make_float4(x_,y_,z_,pp_); } } while (0)

    // ---- pass 1: per-lane sorted top-16 distances over my 2048-pt stream ----
    float nd[16];
    #pragma unroll
    for (int j = 0; j < 16; ++j) nd[j] = 1e30f;

    LOADC(0); WRITEC(0); LOADC(1);
    __syncthreads();
    for (int c = 0; c < 4; ++c) {
        const int pbuf = c & 1;
        #pragma unroll 4
        for (int j = 0; j < 512; ++j) {
            float4 p = sp[pbuf][sub][j];
            float dot = (qp.x * p.x + qp.y * p.y) + qp.z * p.z;
            float d = (qq + p.w) - 2.f * dot;
            if (d < nd[15]) {
                #pragma unroll
                for (int u = 15; u >= 1; --u) nd[u] = med3f(d, nd[u-1], nd[u]);
                nd[0] = fminf(nd[0], d);
            }
        }
        __syncthreads();
        if (c < 3) {
            WRITEC((c + 1) & 1);
            if (c < 2) LOADC(c + 2);
            __syncthreads();
        }
    }
    #pragma unroll
    for (int j = 0; j < 16; ++j) ndl[t][j] = nd[j];
    __syncthreads();

    // leader: exact 16th-smallest via 4-way merge of sorted lists
    if (sub == 0) {
        int p0=0,p1=0,p2=0,p3=0;
        float c0=ndl[t][0], c1=ndl[t+1][0], c2=ndl[t+2][0], c3=ndl[t+3][0];
        float tau = 0.f;
        for (int it = 0; it < 16; ++it) {
            if (c0 <= c1 && c0 <= c2 && c0 <= c3) { tau=c0; ++p0; c0 = (p0<16)?ndl[t][p0]:1e30f; }
            else if (c1 <= c2 && c1 <= c3)        { tau=c1; ++p1; c1 = (p1<16)?ndl[t+1][p1]:1e30f; }
            else if (c2 <= c3)                    { tau=c2; ++p2; c2 = (p2<16)?ndl[t+2][p2]:1e30f; }
            else                                  { tau=c3; ++p3; c3 = (p3<16)?ndl[t+3][p3]:1e30f; }
        }
        taub[qloc] = tau;
    }
    __syncthreads();
    const float tau = taub[qloc];

    // ---- pass 2: collect indices with d <= tau (bit-identical recompute) ----
    int cnt = 0, cless = 0;
    LOADC(0); WRITEC(0); LOADC(1);
    __syncthreads();
    for (int c = 0; c < 4; ++c) {
        const int pbuf = c & 1;
        for (int j = 0; j < 512; ++j) {
            float4 p = sp[pbuf][sub][j];
            float dot = (qp.x * p.x + qp.y * p.y) + qp.z * p.z;
            float d = (qq + p.w) - 2.f * dot;
            if (d <= tau && cnt < CCAP) {
                bool eq = !(d < tau);
                candl[t][cnt++] = (u32)(c * 2048 + sub * 512 + j) | (eq ? 0x80000000u : 0u);
                if (!eq) cless++;
            }
        }
        __syncthreads();
        if (c < 3) {
            WRITEC((c + 1) & 1);
            if (c < 2) LOADC(c + 2);
            __syncthreads();
        }
    }
    ccnt[t] = cnt; ccless[t] = cless;
    __syncthreads();

    // leader: merge 4 candidate streams in ascending point-index order; quota select
    if (sub == 0) {
        int n0=ccnt[t], n1=ccnt[t+1], n2=ccnt[t+2], n3=ccnt[t+3];
        int quota = 16 - (ccless[t]+ccless[t+1]+ccless[t+2]+ccless[t+3]);
        int p0=0,p1=0,p2=0,p3=0, kept=0, eq_used=0;
        u32 h0 = n0 ? candl[t][0]   : 0xFFFFFFFFu;
        u32 h1 = n1 ? candl[t+1][0] : 0xFFFFFFFFu;
        u32 h2 = n2 ? candl[t+2][0] : 0xFFFFFFFFu;
        u32 h3 = n3 ? candl[t+3][0] : 0xFFFFFFFFu;
        size_t obase = (size_t)q * KNN;
        for (int g = 0; g < 4*CCAP && kept < 16; ++g) {
            u32 m0 = h0 & 0x7fffffffu, m1 = h1 & 0x7fffffffu;
            u32 m2 = h2 & 0x7fffffffu, m3 = h3 & 0x7fffffffu;
            u32 v;
            if (m0 <= m1 && m0 <= m2 && m0 <= m3) { v=h0; ++p0; h0 = (p0<n0)?candl[t][p0]:0xFFFFFFFFu; }
            else if (m1 <= m2 && m1 <= m3)        { v=h1; ++p1; h1 = (p1<n1)?candl[t+1][p1]:0xFFFFFFFFu; }
            else if (m2 <= m3)                    { v=h2; ++p2; h2 = (p2<n2)?candl[t+2][p2]:0xFFFFFFFFu; }
            else                                  { v=h3; ++p3; h3 = (p3<n3)?candl[t+3][p3]:0xFFFFFFFFu; }
            if (v == 0xFFFFFFFFu) break;
            bool eq = (v >> 31) != 0;
            bool take = !eq || (eq_used < quota);
            if (take) {
                if (eq) ++eq_used;
                nidx[obase + kept] = b * NPER + (int)(v & 0x7fffffffu);
                ++kept;
            }
        }
    }
    #undef LOADC
    #undef WRITEC
}

// ---------------- fused gather + linear + stats + k-minmax ----------------
__launch_bounds__(128, 4)
__global__ void k_stats(const float* __restrict__ pts, const float* __restrict__ feat,
                        const float* __restrict__ W, const int* __restrict__ nidx,
                        const float4* __restrict__ qpts, float* __restrict__ ymax,
                        float* __restrict__ ymin, float* __restrict__ stats) {
    __shared__ float4 g4[KNN][17];
    const int t = threadIdx.x;
    float w[68];
    const float* wr = W + t * 67;
    #pragma unroll
    for (int c = 0; c < 64; ++c) w[c] = wr[3 + c];
    w[64] = wr[0]; w[65] = wr[1]; w[66] = wr[2]; w[67] = 0.f;

    float s_sum = 0.f, s_sq = 0.f;
    const int k0 = t >> 3, p8 = t & 7;
    for (int mi = 0; mi < 8; ++mi) {
        const int m0 = blockIdx.x * 8 + mi;
        {
            int nid = nidx[(size_t)m0 * KNN + k0];
            const float4* fr = (const float4*)(feat + (size_t)nid * CIN);
            g4[k0][p8*2]   = fr[p8*2];
            g4[k0][p8*2+1] = fr[p8*2+1];
        }
        if (t < 16) {
            int nid = nidx[(size_t)m0 * KNN + t];
            float4 qp = qpts[m0];
            float x = pts[(size_t)nid*3], y = pts[(size_t)nid*3+1], z = pts[(size_t)nid*3+2];
            g4[t][16] = make_float4(x - qp.x, y - qp.y, z - qp.z, 0.f);
        }
        __syncthreads();
        float vmax = -1e30f, vmin = 1e30f;
        #pragma unroll 1
        for (int k = 0; k < KNN; ++k) {
            float y0 = 0.f, y1 = 0.f, y2 = 0.f, y3 = 0.f;
            #pragma unroll
            for (int c4 = 0; c4 < 17; ++c4) {
                float4 gv = g4[k][c4];
                y0 = fmaf(gv.x, w[c4*4+0], y0);
                y1 = fmaf(gv.y, w[c4*4+1], y1);
                y2 = fmaf(gv.z, w[c4*4+2], y2);
                y3 = fmaf(gv.w, w[c4*4+3], y3);
            }
            float y = (y0 + y1) + (y2 + y3);
            vmax = fmaxf(vmax, y); vmin = fminf(vmin, y);
            s_sum += y; s_sq = fmaf(y, y, s_sq);
        }
        ymax[(size_t)m0 * CO + t] = vmax;
        ymin[(size_t)m0 * CO + t] = vmin;
        __syncthreads();
    }
    atomicAdd(stats + t, s_sum);
    atomicAdd(stats + CO + t, s_sq);
}

// ---------------- finalize BN scale/shift ----------------
__global__ void k_final(const float* __restrict__ stats, const float* __restrict__ gamma,
                        const float* __restrict__ beta, float* __restrict__ sb) {
    int o = threadIdx.x;
    const float inv = 1.f / (float)(MTOT * KNN);
    float mean = stats[o] * inv;
    float var = stats[CO + o] * inv - mean * mean;
    var = fmaxf(var, 0.f);
    float s = gamma[o] * rsqrtf(var + 1e-5f);
    sb[o] = s;
    sb[CO + o] = beta[o] - mean * s;
}

// ---------------- epilogue: relu(s*ext + b) ----------------
__global__ void k_out(const float* __restrict__ ymax, const float* __restrict__ ymin,
                      const float* __restrict__ sb, float* __restrict__ out_feat) {
    int tid = blockIdx.x * 256 + threadIdx.x;
    int o = tid & (CO - 1);
    float s = sb[o], bb = sb[CO + o];
    float yv = (s >= 0.f) ? ymax[tid] : ymin[tid];
    out_feat[tid] = fmaxf(fmaf(s, yv, bb), 0.f);
}

extern "C" void kernel_launch(void* const* d_in, const int* in_sizes, int n_in,
                              void* d_out, int out_size, void* d_ws, size_t ws_size,
                              hipStream_t stream) {
    const float* pts   = (const float*)d_in[0];
    const float* feat  = (const float*)d_in[1];
    const float* W     = (const float*)d_in[3];
    const float* gamma = (const float*)d_in[4];
    const float* beta  = (const float*)d_in[5];
    float* out = (float*)d_out;
    char* ws = (char*)d_ws;

    float4* qpts = (float4*)(ws);                       // 131072 B
    int*    nidx = (int*)(ws + 131072);                 // 524288 B
    float*  stats = (float*)(ws + 655360);              // 1024 B
    float*  sb    = (float*)(ws + 656384);              // 1024 B
    float*  ymax  = (float*)(ws + 657408);              // 4 MB
    float*  ymin  = (float*)(ws + 657408 + 4194304);    // 4 MB

    float* out_np   = out;                    // (8192,3)
    float* out_feat = out + 24576;            // (8192,128)
    float* out_rs   = out + 24576 + 1048576;  // (5,)

    hipLaunchKernelGGL(k_init,  dim3(1), dim3(256), 0, stream, stats, out_rs);
    hipLaunchKernelGGL(k_fps,   dim3(NB), dim3(512), 0, stream, pts, out_np, qpts);
    hipLaunchKernelGGL(k_knn,   dim3(MTOT / 64), dim3(256), 0, stream, pts, qpts, nidx);
    hipLaunchKernelGGL(k_stats, dim3(MTOT / 8), dim3(128), 0, stream,
                       pts, feat, W, nidx, qpts, ymax, ymin, stats);
    hipLaunchKernelGGL(k_final, dim3(1), dim3(128), 0, stream, stats, gamma, beta, sb);
    hipLaunchKernelGGL(k_out,   dim3(MTOT * CO / 256), dim3(256), 0, stream,
                       ymax, ymin, sb, out_feat);
}

// Round 7
// 2354.738 us; speedup vs baseline: 1.8139x; 1.0506x over previous
//
#include <hip/hip_runtime.h>

#define NB 4
#define NPER 8192
#define MPER 2048
#define KNN 16
#define CIN 64
#define CO 128
#define MTOT (NB*MPER)
#define CCAP 28

typedef unsigned long long u64;
typedef unsigned int u32;

__device__ __forceinline__ float med3f(float a, float b, float c) {
    return __builtin_amdgcn_fmed3f(a, b, c);
}

// ---------------- init: zero stats + progress, write row_splits ----------------
__global__ void k_init(float* __restrict__ stats, float* __restrict__ rs,
                       u32* __restrict__ prog) {
    int t = threadIdx.x;
    if (t < 256) stats[t] = 0.f;
    if (t < 4) prog[t] = 0u;
    if (t < 5) rs[t] = (float)(t * MPER);
}

// DPP compare-select step on a packed u64 key (max).
#define DPPSTEP(key, CTRL, RM) do {                                                   \
    unsigned lo_ = (unsigned)(key), hi_ = (unsigned)((key) >> 32);                    \
    unsigned nlo = (unsigned)__builtin_amdgcn_update_dpp((int)lo_, (int)lo_, CTRL, RM, 0xf, false); \
    unsigned nhi = (unsigned)__builtin_amdgcn_update_dpp((int)hi_, (int)hi_, CTRL, RM, 0xf, false); \
    unsigned long long ok_ = ((unsigned long long)nhi << 32) | nlo;                   \
    if (ok_ > (key)) (key) = ok_;                                                     \
} while (0)

#define DPP6(key) do { \
    DPPSTEP(key, 0xB1,  0xF); \
    DPPSTEP(key, 0x4E,  0xF); \
    DPPSTEP(key, 0x141, 0xF); \
    DPPSTEP(key, 0x140, 0xF); \
    DPPSTEP(key, 0x142, 0xA); \
    DPPSTEP(key, 0x143, 0xC); \
} while (0)

// ---------------- megakernel: blocks 0-3 = FPS, blocks 4-131 = KNN ----------------
struct FpsSM {
    float4 spt[NPER];          // 128 KiB point table
    u64 red[2][4];             // parity-double-buffered wave partials
};
struct KnnSM {
    float4 sp[2][4][514];
    float  ndl[256][16];
    u32    candl[256][CCAP];
    int    ccnt[256], ccless[256];
    float  taub[64];
};
#define SMBYTES (sizeof(FpsSM) > sizeof(KnnSM) ? sizeof(FpsSM) : sizeof(KnnSM))

__launch_bounds__(256, 1)
__global__ void k_mega(const float* __restrict__ pts, float* __restrict__ out_np,
                       float4* __restrict__ qpts, u32* __restrict__ prog,
                       int* __restrict__ nidx) {
    #pragma clang fp contract(off)
    __shared__ __align__(16) char SMRAW[SMBYTES];
    const int t = threadIdx.x;

    if (blockIdx.x < NB) {
        // ================= FPS (R2-proven body, 256 thr, 32 pts/lane) =================
        FpsSM& sm = *(FpsSM*)SMRAW;
        const int b = blockIdx.x;
        const float4* pb4 = (const float4*)(pts + (size_t)b * NPER * 3);

        float f[96];
        #pragma unroll
        for (int j = 0; j < 24; ++j) {
            float4 v = pb4[t * 24 + j];
            f[j*4+0] = v.x; f[j*4+1] = v.y; f[j*4+2] = v.z; f[j*4+3] = v.w;
        }
        float px[32], py[32], pz[32], dd[32];
        #pragma unroll
        for (int s = 0; s < 32; ++s) {
            px[s] = f[3*s]; py[s] = f[3*s+1]; pz[s] = f[3*s+2];
            dd[s] = 1e10f;
            sm.spt[t * 32 + s] = make_float4(px[s], py[s], pz[s], 0.f);
        }
        if (t == 0) {
            size_t row = (size_t)b * MPER;
            out_np[row*3+0] = px[0]; out_np[row*3+1] = py[0]; out_np[row*3+2] = pz[0];
            qpts[row] = make_float4(px[0], py[0], pz[0], 0.f);
        }
        __syncthreads();

        float4 c0 = sm.spt[0];
        float cx = c0.x, cy = c0.y, cz = c0.z;
        const int lane = t & 63, wv = t >> 6;
        const int ibase = t * 32;

        for (int i = 1; i < MPER; ++i) {
            float bv = -1.f; int bs = 0;
            #pragma unroll
            for (int s = 0; s < 32; ++s) {
                float dx = px[s] - cx, dy = py[s] - cy, dz = pz[s] - cz;
                float t0 = dx * dx, t1 = dy * dy, t2 = dz * dz;
                float d = (t0 + t1) + t2;
                float nd = fminf(dd[s], d);
                dd[s] = nd;
                bool bet = nd > bv;
                bv = bet ? nd : bv;
                bs = bet ? s : bs;
            }
            u64 key = ((u64)__float_as_uint(bv) << 32) | (u32)~(u32)(ibase + bs);

            DPP6(key);

            if (lane == 63) sm.red[i & 1][wv] = key;
            __syncthreads();

            const int p = i & 1;
            u64 k0 = sm.red[p][0], k1 = sm.red[p][1], k2 = sm.red[p][2], k3 = sm.red[p][3];
            u64 ka = k0 > k1 ? k0 : k1;
            u64 kb = k2 > k3 ? k2 : k3;
            u64 kbest = ka > kb ? ka : kb;
            const int i2 = (int)(~(u32)kbest) & 0x1FFF;

            float4 c = sm.spt[i2];
            cx = c.x; cy = c.y; cz = c.z;

            if (t == 0) {
                size_t row = (size_t)b * MPER + i;
                out_np[row*3+0] = cx; out_np[row*3+1] = cy; out_np[row*3+2] = cz;
                qpts[row] = make_float4(cx, cy, cz, 0.f);
                if ((i & 63) == 63) {
                    __threadfence();
                    __hip_atomic_store(prog + b, (u32)(i + 1),
                                       __ATOMIC_RELEASE, __HIP_MEMORY_SCOPE_AGENT);
                }
            }
        }
    } else {
        // ================= KNN (R4-proven body), gated on FPS progress =================
        KnnSM& sm = *(KnnSM*)SMRAW;
        const int kb = blockIdx.x - NB;
        const int q0 = kb * 64;
        const int b = q0 >> 11;
        const u32 need = (u32)(((q0 + 63) & (MPER - 1)) + 1);

        // spin until our 64 query rows are published (all threads, same address)
        while (__hip_atomic_load(prog + b, __ATOMIC_RELAXED, __HIP_MEMORY_SCOPE_AGENT) < need)
            __builtin_amdgcn_s_sleep(8);
        __threadfence();

        const int qloc = t >> 2, sub = t & 3;
        const int q = q0 + qloc;
        const float4 qp = qpts[q];
        const float qq = (qp.x * qp.x + qp.y * qp.y) + qp.z * qp.z;
        const float* pb = pts + (size_t)b * NPER * 3;
        const int wq = t >> 6, wl = t & 63;

        float4 L[6];
        #define LOADC(c) do { const float4* src_ = (const float4*)(pb + (size_t)(c) * 2048 * 3); \
            _Pragma("unroll") for (int u_ = 0; u_ < 6; ++u_) L[u_] = src_[t * 6 + u_]; } while (0)
        #define WRITEC(pbuf) do { \
            float fl_[24]; \
            _Pragma("unroll") for (int u_ = 0; u_ < 6; ++u_) { \
                fl_[u_*4+0]=L[u_].x; fl_[u_*4+1]=L[u_].y; fl_[u_*4+2]=L[u_].z; fl_[u_*4+3]=L[u_].w; } \
            _Pragma("unroll") for (int r_ = 0; r_ < 8; ++r_) { \
                float x_=fl_[3*r_], y_=fl_[3*r_+1], z_=fl_[3*r_+2]; \
                float pp_=(x_*x_ + y_*y_) + z_*z_; \
                sm.sp[pbuf][wq][wl*8 + r_] = make_float4(x_,y_,z_,pp_); } } while (0)

        // ---- pass 1 ----
        float nd[16];
        #pragma unroll
        for (int j = 0; j < 16; ++j) nd[j] = 1e30f;

        LOADC(0); WRITEC(0); LOADC(1);
        __syncthreads();
        for (int c = 0; c < 4; ++c) {
            const int pbuf = c & 1;
            #pragma unroll 4
            for (int j = 0; j < 512; ++j) {
                float4 p = sm.sp[pbuf][sub][j];
                float dot = (qp.x * p.x + qp.y * p.y) + qp.z * p.z;
                float d = (qq + p.w) - 2.f * dot;
                if (d < nd[15]) {
                    #pragma unroll
                    for (int u = 15; u >= 1; --u) nd[u] = med3f(d, nd[u-1], nd[u]);
                    nd[0] = fminf(nd[0], d);
                }
            }
            __syncthreads();
            if (c < 3) {
                WRITEC((c + 1) & 1);
                if (c < 2) LOADC(c + 2);
                __syncthreads();
            }
        }
        #pragma unroll
        for (int j = 0; j < 16; ++j) sm.ndl[t][j] = nd[j];
        __syncthreads();

        if (sub == 0) {
            int p0=0,p1=0,p2=0,p3=0;
            float c0=sm.ndl[t][0], c1=sm.ndl[t+1][0], c2=sm.ndl[t+2][0], c3=sm.ndl[t+3][0];
            float tau = 0.f;
            for (int it = 0; it < 16; ++it) {
                if (c0 <= c1 && c0 <= c2 && c0 <= c3) { tau=c0; ++p0; c0 = (p0<16)?sm.ndl[t][p0]:1e30f; }
                else if (c1 <= c2 && c1 <= c3)        { tau=c1; ++p1; c1 = (p1<16)?sm.ndl[t+1][p1]:1e30f; }
                else if (c2 <= c3)                    { tau=c2; ++p2; c2 = (p2<16)?sm.ndl[t+2][p2]:1e30f; }
                else                                  { tau=c3; ++p3; c3 = (p3<16)?sm.ndl[t+3][p3]:1e30f; }
            }
            sm.taub[qloc] = tau;
        }
        __syncthreads();
        const float tau = sm.taub[qloc];

        // ---- pass 2 ----
        int cnt = 0, cless = 0;
        LOADC(0); WRITEC(0); LOADC(1);
        __syncthreads();
        for (int c = 0; c < 4; ++c) {
            const int pbuf = c & 1;
            for (int j = 0; j < 512; ++j) {
                float4 p = sm.sp[pbuf][sub][j];
                float dot = (qp.x * p.x + qp.y * p.y) + qp.z * p.z;
                float d = (qq + p.w) - 2.f * dot;
                if (d <= tau && cnt < CCAP) {
                    bool eq = !(d < tau);
                    sm.candl[t][cnt++] = (u32)(c * 2048 + sub * 512 + j) | (eq ? 0x80000000u : 0u);
                    if (!eq) cless++;
                }
            }
            __syncthreads();
            if (c < 3) {
                WRITEC((c + 1) & 1);
                if (c < 2) LOADC(c + 2);
                __syncthreads();
            }
        }
        sm.ccnt[t] = cnt; sm.ccless[t] = cless;
        __syncthreads();

        if (sub == 0) {
            int n0=sm.ccnt[t], n1=sm.ccnt[t+1], n2=sm.ccnt[t+2], n3=sm.ccnt[t+3];
            int quota = 16 - (sm.ccless[t]+sm.ccless[t+1]+sm.ccless[t+2]+sm.ccless[t+3]);
            int p0=0,p1=0,p2=0,p3=0, kept=0, eq_used=0;
            u32 h0 = n0 ? sm.candl[t][0]   : 0xFFFFFFFFu;
            u32 h1 = n1 ? sm.candl[t+1][0] : 0xFFFFFFFFu;
            u32 h2 = n2 ? sm.candl[t+2][0] : 0xFFFFFFFFu;
            u32 h3 = n3 ? sm.candl[t+3][0] : 0xFFFFFFFFu;
            size_t obase = (size_t)q * KNN;
            for (int g = 0; g < 4*CCAP && kept < 16; ++g) {
                u32 m0 = h0 & 0x7fffffffu, m1 = h1 & 0x7fffffffu;
                u32 m2 = h2 & 0x7fffffffu, m3 = h3 & 0x7fffffffu;
                u32 v;
                if (m0 <= m1 && m0 <= m2 && m0 <= m3) { v=h0; ++p0; h0 = (p0<n0)?sm.candl[t][p0]:0xFFFFFFFFu; }
                else if (m1 <= m2 && m1 <= m3)        { v=h1; ++p1; h1 = (p1<n1)?sm.candl[t+1][p1]:0xFFFFFFFFu; }
                else if (m2 <= m3)                    { v=h2; ++p2; h2 = (p2<n2)?sm.candl[t+2][p2]:0xFFFFFFFFu; }
                else                                  { v=h3; ++p3; h3 = (p3<n3)?sm.candl[t+3][p3]:0xFFFFFFFFu; }
                if (v == 0xFFFFFFFFu) break;
                bool eq = (v >> 31) != 0;
                bool take = !eq || (eq_used < quota);
                if (take) {
                    if (eq) ++eq_used;
                    nidx[obase + kept] = b * NPER + (int)(v & 0x7fffffffu);
                    ++kept;
                }
            }
        }
        #undef LOADC
        #undef WRITEC
    }
}

// ---------------- fused gather + linear + stats + k-minmax ----------------
__launch_bounds__(128, 4)
__global__ void k_stats(const float* __restrict__ pts, const float* __restrict__ feat,
                        const float* __restrict__ W, const int* __restrict__ nidx,
                        const float4* __restrict__ qpts, float* __restrict__ ymax,
                        float* __restrict__ ymin, float* __restrict__ stats) {
    __shared__ float4 g4[KNN][17];
    const int t = threadIdx.x;
    float w[68];
    const float* wr = W + t * 67;
    #pragma unroll
    for (int c = 0; c < 64; ++c) w[c] = wr[3 + c];
    w[64] = wr[0]; w[65] = wr[1]; w[66] = wr[2]; w[67] = 0.f;

    float s_sum = 0.f, s_sq = 0.f;
    const int k0 = t >> 3, p8 = t & 7;
    for (int mi = 0; mi < 8; ++mi) {
        const int m0 = blockIdx.x * 8 + mi;
        {
            int nid = nidx[(size_t)m0 * KNN + k0];
            const float4* fr = (const float4*)(feat + (size_t)nid * CIN);
            g4[k0][p8*2]   = fr[p8*2];
            g4[k0][p8*2+1] = fr[p8*2+1];
        }
        if (t < 16) {
            int nid = nidx[(size_t)m0 * KNN + t];
            float4 qp = qpts[m0];
            float x = pts[(size_t)nid*3], y = pts[(size_t)nid*3+1], z = pts[(size_t)nid*3+2];
            g4[t][16] = make_float4(x - qp.x, y - qp.y, z - qp.z, 0.f);
        }
        __syncthreads();
        float vmax = -1e30f, vmin = 1e30f;
        #pragma unroll 1
        for (int k = 0; k < KNN; ++k) {
            float y0 = 0.f, y1 = 0.f, y2 = 0.f, y3 = 0.f;
            #pragma unroll
            for (int c4 = 0; c4 < 17; ++c4) {
                float4 gv = g4[k][c4];
                y0 = fmaf(gv.x, w[c4*4+0], y0);
                y1 = fmaf(gv.y, w[c4*4+1], y1);
                y2 = fmaf(gv.z, w[c4*4+2], y2);
                y3 = fmaf(gv.w, w[c4*4+3], y3);
            }
            float y = (y0 + y1) + (y2 + y3);
            vmax = fmaxf(vmax, y); vmin = fminf(vmin, y);
            s_sum += y; s_sq = fmaf(y, y, s_sq);
        }
        ymax[(size_t)m0 * CO + t] = vmax;
        ymin[(size_t)m0 * CO + t] = vmin;
        __syncthreads();
    }
    atomicAdd(stats + t, s_sum);
    atomicAdd(stats + CO + t, s_sq);
}

// ---------------- epilogue: BN finalize (inlined) + relu(s*ext + b) ----------------
__global__ void k_out(const float* __restrict__ ymax, const float* __restrict__ ymin,
                      const float* __restrict__ stats, const float* __restrict__ gamma,
                      const float* __restrict__ beta, float* __restrict__ out_feat) {
    int tid = blockIdx.x * 256 + threadIdx.x;
    int o = tid & (CO - 1);
    const float inv = 1.f / (float)(MTOT * KNN);
    float mean = stats[o] * inv;
    float var = stats[CO + o] * inv - mean * mean;
    var = fmaxf(var, 0.f);
    float s = gamma[o] * rsqrtf(var + 1e-5f);
    float bb = beta[o] - mean * s;
    float yv = (s >= 0.f) ? ymax[tid] : ymin[tid];
    out_feat[tid] = fmaxf(fmaf(s, yv, bb), 0.f);
}

extern "C" void kernel_launch(void* const* d_in, const int* in_sizes, int n_in,
                              void* d_out, int out_size, void* d_ws, size_t ws_size,
                              hipStream_t stream) {
    const float* pts   = (const float*)d_in[0];
    const float* feat  = (const float*)d_in[1];
    const float* W     = (const float*)d_in[3];
    const float* gamma = (const float*)d_in[4];
    const float* beta  = (const float*)d_in[5];
    float* out = (float*)d_out;
    char* ws = (char*)d_ws;

    float4* qpts = (float4*)(ws);                       // 131072 B
    int*    nidx = (int*)(ws + 131072);                 // 524288 B
    float*  stats = (float*)(ws + 655360);              // 1024 B
    u32*    prog  = (u32*)(ws + 656384);                // 16 B
    float*  ymax  = (float*)(ws + 657408);              // 4 MB
    float*  ymin  = (float*)(ws + 657408 + 4194304);    // 4 MB

    float* out_np   = out;                    // (8192,3)
    float* out_feat = out + 24576;            // (8192,128)
    float* out_rs   = out + 24576 + 1048576;  // (5,)

    hipLaunchKernelGGL(k_init,  dim3(1), dim3(256), 0, stream, stats, out_rs, prog);
    hipLaunchKernelGGL(k_mega,  dim3(NB + MTOT / 64), dim3(256), 0, stream,
                       pts, out_np, qpts, prog, nidx);
    hipLaunchKernelGGL(k_stats, dim3(MTOT / 8), dim3(128), 0, stream,
                       pts, feat, W, nidx, qpts, ymax, ymin, stats);
    hipLaunchKernelGGL(k_out,   dim3(MTOT * CO / 256), dim3(256), 0, stream,
                       ymax, ymin, stats, gamma, beta, out_feat);
}

// Round 8
// 2323.994 us; speedup vs baseline: 1.8379x; 1.0132x over previous
//
#include <hip/hip_runtime.h>

#define NB 4
#define NPER 8192
#define MPER 2048
#define KNN 16
#define CIN 64
#define CO 128
#define MTOT (NB*MPER)
#define CCAP 28

typedef unsigned long long u64;
typedef unsigned int u32;

__device__ __forceinline__ float med3f(float a, float b, float c) {
    return __builtin_amdgcn_fmed3f(a, b, c);
}

// ---------------- init: zero stats + progress, write row_splits ----------------
__global__ void k_init(float* __restrict__ stats, float* __restrict__ rs,
                       u32* __restrict__ prog) {
    int t = threadIdx.x;
    if (t < 256) stats[t] = 0.f;
    if (t < 128) prog[t] = 0u;
    if (t < 5) rs[t] = (float)(t * MPER);
}

// DPP compare-select step on a packed u64 key (max).
#define DPPSTEP(key, CTRL, RM) do {                                                   \
    unsigned lo_ = (unsigned)(key), hi_ = (unsigned)((key) >> 32);                    \
    unsigned nlo = (unsigned)__builtin_amdgcn_update_dpp((int)lo_, (int)lo_, CTRL, RM, 0xf, false); \
    unsigned nhi = (unsigned)__builtin_amdgcn_update_dpp((int)hi_, (int)hi_, CTRL, RM, 0xf, false); \
    unsigned long long ok_ = ((unsigned long long)nhi << 32) | nlo;                   \
    if (ok_ > (key)) (key) = ok_;                                                     \
} while (0)

#define DPP6(key) do { \
    DPPSTEP(key, 0xB1,  0xF); \
    DPPSTEP(key, 0x4E,  0xF); \
    DPPSTEP(key, 0x141, 0xF); \
    DPPSTEP(key, 0x140, 0xF); \
    DPPSTEP(key, 0x142, 0xA); \
    DPPSTEP(key, 0x143, 0xC); \
} while (0)

// ---------------- megakernel: blocks 0-3 = FPS, blocks 4-131 = KNN ----------------
struct FpsSM {
    float4 spt[NPER];          // 128 KiB point table
    u64 red[2][4];             // parity-double-buffered wave partials
};
struct KnnSM {
    float4 sp[2][4][514];
    float  ndl[256][16];
    u32    candl[256][CCAP];
    int    ccnt[256], ccless[256];
    float  taub[64];
};
#define SMBYTES (sizeof(FpsSM) > sizeof(KnnSM) ? sizeof(FpsSM) : sizeof(KnnSM))

__launch_bounds__(256, 1)
__global__ void k_mega(const float* __restrict__ pts, float* __restrict__ out_np,
                       float4* __restrict__ qpts, u32* __restrict__ prog,
                       int* __restrict__ nidx) {
    #pragma clang fp contract(off)
    __shared__ __align__(16) char SMRAW[SMBYTES];
    const int t = threadIdx.x;

    if (blockIdx.x < NB) {
        // ================= FPS (R2-proven body, 256 thr, 32 pts/lane) =================
        FpsSM& sm = *(FpsSM*)SMRAW;
        const int b = blockIdx.x;
        const float4* pb4 = (const float4*)(pts + (size_t)b * NPER * 3);

        float f[96];
        #pragma unroll
        for (int j = 0; j < 24; ++j) {
            float4 v = pb4[t * 24 + j];
            f[j*4+0] = v.x; f[j*4+1] = v.y; f[j*4+2] = v.z; f[j*4+3] = v.w;
        }
        float px[32], py[32], pz[32], dd[32];
        #pragma unroll
        for (int s = 0; s < 32; ++s) {
            px[s] = f[3*s]; py[s] = f[3*s+1]; pz[s] = f[3*s+2];
            dd[s] = 1e10f;
            sm.spt[t * 32 + s] = make_float4(px[s], py[s], pz[s], 0.f);
        }
        if (t == 0) {
            size_t row = (size_t)b * MPER;
            out_np[row*3+0] = px[0]; out_np[row*3+1] = py[0]; out_np[row*3+2] = pz[0];
            qpts[row] = make_float4(px[0], py[0], pz[0], 0.f);
        }
        __syncthreads();

        float4 c0 = sm.spt[0];
        float cx = c0.x, cy = c0.y, cz = c0.z;
        const int lane = t & 63, wv = t >> 6;
        const int ibase = t * 32;

        for (int i = 1; i < MPER; ++i) {
            float bv = -1.f; int bs = 0;
            #pragma unroll
            for (int s = 0; s < 32; ++s) {
                float dx = px[s] - cx, dy = py[s] - cy, dz = pz[s] - cz;
                float t0 = dx * dx, t1 = dy * dy, t2 = dz * dz;
                float d = (t0 + t1) + t2;
                float nd = fminf(dd[s], d);
                dd[s] = nd;
                bool bet = nd > bv;
                bv = bet ? nd : bv;
                bs = bet ? s : bs;
            }
            u64 key = ((u64)__float_as_uint(bv) << 32) | (u32)~(u32)(ibase + bs);

            DPP6(key);

            if (lane == 63) sm.red[i & 1][wv] = key;
            __syncthreads();

            const int p = i & 1;
            u64 k0 = sm.red[p][0], k1 = sm.red[p][1], k2 = sm.red[p][2], k3 = sm.red[p][3];
            u64 ka = k0 > k1 ? k0 : k1;
            u64 kb = k2 > k3 ? k2 : k3;
            u64 kbest = ka > kb ? ka : kb;
            const int i2 = (int)(~(u32)kbest) & 0x1FFF;

            float4 c = sm.spt[i2];
            cx = c.x; cy = c.y; cz = c.z;

            if (t == 0) {
                size_t row = (size_t)b * MPER + i;
                out_np[row*3+0] = cx; out_np[row*3+1] = cy; out_np[row*3+2] = cz;
                qpts[row] = make_float4(cx, cy, cz, 0.f);
                if ((i & 127) == 127) {
                    __threadfence();
                    __hip_atomic_store(prog + b * 32, (u32)(i + 1),
                                       __ATOMIC_RELEASE, __HIP_MEMORY_SCOPE_AGENT);
                }
            }
        }
    } else {
        // ================= KNN (R4-proven body), gated on FPS progress =================
        KnnSM& sm = *(KnnSM*)SMRAW;
        const int kb = blockIdx.x - NB;
        const int q0 = kb * 64;
        const int b = q0 >> 11;
        const u32 need = (u32)(((q0 + 63) & (MPER - 1)) + 1);

        // single-thread spin (de-storm the coherence point), then block-wide fence
        if (t == 0) {
            while (__hip_atomic_load(prog + b * 32, __ATOMIC_RELAXED,
                                     __HIP_MEMORY_SCOPE_AGENT) < need)
                __builtin_amdgcn_s_sleep(32);
        }
        __syncthreads();
        __threadfence();

        const int qloc = t >> 2, sub = t & 3;
        const int q = q0 + qloc;
        const float4 qp = qpts[q];
        const float qq = (qp.x * qp.x + qp.y * qp.y) + qp.z * qp.z;
        const float* pb = pts + (size_t)b * NPER * 3;
        const int wq = t >> 6, wl = t & 63;

        float4 L[6];
        #define LOADC(c) do { const float4* src_ = (const float4*)(pb + (size_t)(c) * 2048 * 3); \
            _Pragma("unroll") for (int u_ = 0; u_ < 6; ++u_) L[u_] = src_[t * 6 + u_]; } while (0)
        #define WRITEC(pbuf) do { \
            float fl_[24]; \
            _Pragma("unroll") for (int u_ = 0; u_ < 6; ++u_) { \
                fl_[u_*4+0]=L[u_].x; fl_[u_*4+1]=L[u_].y; fl_[u_*4+2]=L[u_].z; fl_[u_*4+3]=L[u_].w; } \
            _Pragma("unroll") for (int r_ = 0; r_ < 8; ++r_) { \
                float x_=fl_[3*r_], y_=fl_[3*r_+1], z_=fl_[3*r_+2]; \
                float pp_=(x_*x_ + y_*y_) + z_*z_; \
                sm.sp[pbuf][wq][wl*8 + r_] = make_float4(x_,y_,z_,pp_); } } while (0)

        // ---- pass 1 ----
        float nd[16];
        #pragma unroll
        for (int j = 0; j < 16; ++j) nd[j] = 1e30f;

        LOADC(0); WRITEC(0); LOADC(1);
        __syncthreads();
        for (int c = 0; c < 4; ++c) {
            const int pbuf = c & 1;
            #pragma unroll 4
            for (int j = 0; j < 512; ++j) {
                float4 p = sm.sp[pbuf][sub][j];
                float dot = (qp.x * p.x + qp.y * p.y) + qp.z * p.z;
                float d = (qq + p.w) - 2.f * dot;
                if (d < nd[15]) {
                    #pragma unroll
                    for (int u = 15; u >= 1; --u) nd[u] = med3f(d, nd[u-1], nd[u]);
                    nd[0] = fminf(nd[0], d);
                }
            }
            __syncthreads();
            if (c < 3) {
                WRITEC((c + 1) & 1);
                if (c < 2) LOADC(c + 2);
                __syncthreads();
            }
        }
        #pragma unroll
        for (int j = 0; j < 16; ++j) sm.ndl[t][j] = nd[j];
        __syncthreads();

        if (sub == 0) {
            int p0=0,p1=0,p2=0,p3=0;
            float c0=sm.ndl[t][0], c1=sm.ndl[t+1][0], c2=sm.ndl[t+2][0], c3=sm.ndl[t+3][0];
            float tau = 0.f;
            for (int it = 0; it < 16; ++it) {
                if (c0 <= c1 && c0 <= c2 && c0 <= c3) { tau=c0; ++p0; c0 = (p0<16)?sm.ndl[t][p0]:1e30f; }
                else if (c1 <= c2 && c1 <= c3)        { tau=c1; ++p1; c1 = (p1<16)?sm.ndl[t+1][p1]:1e30f; }
                else if (c2 <= c3)                    { tau=c2; ++p2; c2 = (p2<16)?sm.ndl[t+2][p2]:1e30f; }
                else                                  { tau=c3; ++p3; c3 = (p3<16)?sm.ndl[t+3][p3]:1e30f; }
            }
            sm.taub[qloc] = tau;
        }
        __syncthreads();
        const float tau = sm.taub[qloc];

        // ---- pass 2 ----
        int cnt = 0, cless = 0;
        LOADC(0); WRITEC(0); LOADC(1);
        __syncthreads();
        for (int c = 0; c < 4; ++c) {
            const int pbuf = c & 1;
            for (int j = 0; j < 512; ++j) {
                float4 p = sm.sp[pbuf][sub][j];
                float dot = (qp.x * p.x + qp.y * p.y) + qp.z * p.z;
                float d = (qq + p.w) - 2.f * dot;
                if (d <= tau && cnt < CCAP) {
                    bool eq = !(d < tau);
                    sm.candl[t][cnt++] = (u32)(c * 2048 + sub * 512 + j) | (eq ? 0x80000000u : 0u);
                    if (!eq) cless++;
                }
            }
            __syncthreads();
            if (c < 3) {
                WRITEC((c + 1) & 1);
                if (c < 2) LOADC(c + 2);
                __syncthreads();
            }
        }
        sm.ccnt[t] = cnt; sm.ccless[t] = cless;
        __syncthreads();

        if (sub == 0) {
            int n0=sm.ccnt[t], n1=sm.ccnt[t+1], n2=sm.ccnt[t+2], n3=sm.ccnt[t+3];
            int quota = 16 - (sm.ccless[t]+sm.ccless[t+1]+sm.ccless[t+2]+sm.ccless[t+3]);
            int p0=0,p1=0,p2=0,p3=0, kept=0, eq_used=0;
            u32 h0 = n0 ? sm.candl[t][0]   : 0xFFFFFFFFu;
            u32 h1 = n1 ? sm.candl[t+1][0] : 0xFFFFFFFFu;
            u32 h2 = n2 ? sm.candl[t+2][0] : 0xFFFFFFFFu;
            u32 h3 = n3 ? sm.candl[t+3][0] : 0xFFFFFFFFu;
            size_t obase = (size_t)q * KNN;
            for (int g = 0; g < 4*CCAP && kept < 16; ++g) {
                u32 m0 = h0 & 0x7fffffffu, m1 = h1 & 0x7fffffffu;
                u32 m2 = h2 & 0x7fffffffu, m3 = h3 & 0x7fffffffu;
                u32 v;
                if (m0 <= m1 && m0 <= m2 && m0 <= m3) { v=h0; ++p0; h0 = (p0<n0)?sm.candl[t][p0]:0xFFFFFFFFu; }
                else if (m1 <= m2 && m1 <= m3)        { v=h1; ++p1; h1 = (p1<n1)?sm.candl[t+1][p1]:0xFFFFFFFFu; }
                else if (m2 <= m3)                    { v=h2; ++p2; h2 = (p2<n2)?sm.candl[t+2][p2]:0xFFFFFFFFu; }
                else                                  { v=h3; ++p3; h3 = (p3<n3)?sm.candl[t+3][p3]:0xFFFFFFFFu; }
                if (v == 0xFFFFFFFFu) break;
                bool eq = (v >> 31) != 0;
                bool take = !eq || (eq_used < quota);
                if (take) {
                    if (eq) ++eq_used;
                    nidx[obase + kept] = b * NPER + (int)(v & 0x7fffffffu);
                    ++kept;
                }
            }
        }
        #undef LOADC
        #undef WRITEC
    }
}

// ---------------- fused gather + linear + stats + k-minmax ----------------
__launch_bounds__(128, 4)
__global__ void k_stats(const float* __restrict__ pts, const float* __restrict__ feat,
                        const float* __restrict__ W, const int* __restrict__ nidx,
                        const float4* __restrict__ qpts, float* __restrict__ ymax,
                        float* __restrict__ ymin, float* __restrict__ stats) {
    __shared__ float4 g4[KNN][17];
    const int t = threadIdx.x;
    float w[68];
    const float* wr = W + t * 67;
    #pragma unroll
    for (int c = 0; c < 64; ++c) w[c] = wr[3 + c];
    w[64] = wr[0]; w[65] = wr[1]; w[66] = wr[2]; w[67] = 0.f;

    float s_sum = 0.f, s_sq = 0.f;
    const int k0 = t >> 3, p8 = t & 7;
    for (int mi = 0; mi < 8; ++mi) {
        const int m0 = blockIdx.x * 8 + mi;
        {
            int nid = nidx[(size_t)m0 * KNN + k0];
            const float4* fr = (const float4*)(feat + (size_t)nid * CIN);
            g4[k0][p8*2]   = fr[p8*2];
            g4[k0][p8*2+1] = fr[p8*2+1];
        }
        if (t < 16) {
            int nid = nidx[(size_t)m0 * KNN + t];
            float4 qp = qpts[m0];
            float x = pts[(size_t)nid*3], y = pts[(size_t)nid*3+1], z = pts[(size_t)nid*3+2];
            g4[t][16] = make_float4(x - qp.x, y - qp.y, z - qp.z, 0.f);
        }
        __syncthreads();
        float vmax = -1e30f, vmin = 1e30f;
        #pragma unroll 1
        for (int k = 0; k < KNN; ++k) {
            float y0 = 0.f, y1 = 0.f, y2 = 0.f, y3 = 0.f;
            #pragma unroll
            for (int c4 = 0; c4 < 17; ++c4) {
                float4 gv = g4[k][c4];
                y0 = fmaf(gv.x, w[c4*4+0], y0);
                y1 = fmaf(gv.y, w[c4*4+1], y1);
                y2 = fmaf(gv.z, w[c4*4+2], y2);
                y3 = fmaf(gv.w, w[c4*4+3], y3);
            }
            float y = (y0 + y1) + (y2 + y3);
            vmax = fmaxf(vmax, y); vmin = fminf(vmin, y);
            s_sum += y; s_sq = fmaf(y, y, s_sq);
        }
        ymax[(size_t)m0 * CO + t] = vmax;
        ymin[(size_t)m0 * CO + t] = vmin;
        __syncthreads();
    }
    atomicAdd(stats + t, s_sum);
    atomicAdd(stats + CO + t, s_sq);
}

// ---------------- epilogue: BN finalize (inlined) + relu(s*ext + b) ----------------
__global__ void k_out(const float* __restrict__ ymax, const float* __restrict__ ymin,
                      const float* __restrict__ stats, const float* __restrict__ gamma,
                      const float* __restrict__ beta, float* __restrict__ out_feat) {
    int tid = blockIdx.x * 256 + threadIdx.x;
    int o = tid & (CO - 1);
    const float inv = 1.f / (float)(MTOT * KNN);
    float mean = stats[o] * inv;
    float var = stats[CO + o] * inv - mean * mean;
    var = fmaxf(var, 0.f);
    float s = gamma[o] * rsqrtf(var + 1e-5f);
    float bb = beta[o] - mean * s;
    float yv = (s >= 0.f) ? ymax[tid] : ymin[tid];
    out_feat[tid] = fmaxf(fmaf(s, yv, bb), 0.f);
}

extern "C" void kernel_launch(void* const* d_in, const int* in_sizes, int n_in,
                              void* d_out, int out_size, void* d_ws, size_t ws_size,
                              hipStream_t stream) {
    const float* pts   = (const float*)d_in[0];
    const float* feat  = (const float*)d_in[1];
    const float* W     = (const float*)d_in[3];
    const float* gamma = (const float*)d_in[4];
    const float* beta  = (const float*)d_in[5];
    float* out = (float*)d_out;
    char* ws = (char*)d_ws;

    float4* qpts = (float4*)(ws);                       // 131072 B
    int*    nidx = (int*)(ws + 131072);                 // 524288 B
    float*  stats = (float*)(ws + 655360);              // 1024 B
    u32*    prog  = (u32*)(ws + 656384);                // 512 B (4 batches x 128B apart)
    float*  ymax  = (float*)(ws + 657408);              // 4 MB
    float*  ymin  = (float*)(ws + 657408 + 4194304);    // 4 MB

    float* out_np   = out;                    // (8192,3)
    float* out_feat = out + 24576;            // (8192,128)
    float* out_rs   = out + 24576 + 1048576;  // (5,)

    hipLaunchKernelGGL(k_init,  dim3(1), dim3(256), 0, stream, stats, out_rs, prog);
    hipLaunchKernelGGL(k_mega,  dim3(NB + MTOT / 64), dim3(256), 0, stream,
                       pts, out_np, qpts, prog, nidx);
    hipLaunchKernelGGL(k_stats, dim3(MTOT / 8), dim3(128), 0, stream,
                       pts, feat, W, nidx, qpts, ymax, ymin, stats);
    hipLaunchKernelGGL(k_out,   dim3(MTOT * CO / 256), dim3(256), 0, stream,
                       ymax, ymin, stats, gamma, beta, out_feat);
}

// Round 9
// 2055.143 us; speedup vs baseline: 2.0783x; 1.1308x over previous
//
#include <hip/hip_runtime.h>

#define NB 4
#define NPER 8192
#define MPER 2048
#define KNN 16
#define CIN 64
#define CO 128
#define MTOT (NB*MPER)
#define CPB 56          // knn chunks per batch: 24x64q + 8x32q + 8x16q + 16x8q

typedef unsigned long long u64;
typedef unsigned int u32;

__device__ __forceinline__ float med3f(float a, float b, float c) {
    return __builtin_amdgcn_fmed3f(a, b, c);
}

// ---------------- init: zero stats + progress, write row_splits ----------------
__global__ void k_init(float* __restrict__ stats, float* __restrict__ rs,
                       u32* __restrict__ prog) {
    int t = threadIdx.x;
    if (t < 256) stats[t] = 0.f;
    if (t < 128) prog[t] = 0u;
    if (t < 5) rs[t] = (float)(t * MPER);
}

// DPP compare-select step on a packed u64 key (max).
#define DPPSTEP(key, CTRL, RM) do {                                                   \
    unsigned lo_ = (unsigned)(key), hi_ = (unsigned)((key) >> 32);                    \
    unsigned nlo = (unsigned)__builtin_amdgcn_update_dpp((int)lo_, (int)lo_, CTRL, RM, 0xf, false); \
    unsigned nhi = (unsigned)__builtin_amdgcn_update_dpp((int)hi_, (int)hi_, CTRL, RM, 0xf, false); \
    unsigned long long ok_ = ((unsigned long long)nhi << 32) | nlo;                   \
    if (ok_ > (key)) (key) = ok_;                                                     \
} while (0)

#define DPP6(key) do { \
    DPPSTEP(key, 0xB1,  0xF); \
    DPPSTEP(key, 0x4E,  0xF); \
    DPPSTEP(key, 0x141, 0xF); \
    DPPSTEP(key, 0x140, 0xF); \
    DPPSTEP(key, 0x142, 0xA); \
    DPPSTEP(key, 0x143, 0xC); \
} while (0)

// ---------------- megakernel: blocks 0-3 = FPS, blocks 4-227 = KNN ----------------
struct FpsSM {
    float4 spt[NPER];          // 128 KiB point table
    u64 red[2][4];             // parity-double-buffered wave partials
};
struct KnnSM {
    float4 sp[2][2112];        // staged chunk, per-sub stride P+2 (bank-safe)
    float  ndl[256][16];
    u32    candl[256][16];     // d < tau candidates (globally <= 15)
    u32    eql[256][16];       // d == tau candidates
    int    ccnt[256], ecnt[256];
    u32    pcur[256];
    float  taub[64];
};
#define SMBYTES (sizeof(FpsSM) > sizeof(KnnSM) ? sizeof(FpsSM) : sizeof(KnnSM))

__launch_bounds__(256, 1)
__global__ void k_mega(const float* __restrict__ pts, float* __restrict__ out_np,
                       float4* __restrict__ qpts, u32* __restrict__ prog,
                       int* __restrict__ nidx) {
    #pragma clang fp contract(off)
    __shared__ __align__(16) char SMRAW[SMBYTES];
    const int t = threadIdx.x;

    if (blockIdx.x < NB) {
        // ================= FPS (R2-proven body, 256 thr, 32 pts/lane) =================
        FpsSM& sm = *(FpsSM*)SMRAW;
        const int b = blockIdx.x;
        const float4* pb4 = (const float4*)(pts + (size_t)b * NPER * 3);

        float f[96];
        #pragma unroll
        for (int j = 0; j < 24; ++j) {
            float4 v = pb4[t * 24 + j];
            f[j*4+0] = v.x; f[j*4+1] = v.y; f[j*4+2] = v.z; f[j*4+3] = v.w;
        }
        float px[32], py[32], pz[32], dd[32];
        #pragma unroll
        for (int s = 0; s < 32; ++s) {
            px[s] = f[3*s]; py[s] = f[3*s+1]; pz[s] = f[3*s+2];
            dd[s] = 1e10f;
            sm.spt[t * 32 + s] = make_float4(px[s], py[s], pz[s], 0.f);
        }
        if (t == 0) {
            size_t row = (size_t)b * MPER;
            out_np[row*3+0] = px[0]; out_np[row*3+1] = py[0]; out_np[row*3+2] = pz[0];
            qpts[row] = make_float4(px[0], py[0], pz[0], 0.f);
        }
        __syncthreads();

        float4 c0 = sm.spt[0];
        float cx = c0.x, cy = c0.y, cz = c0.z;
        const int lane = t & 63, wv = t >> 6;
        const int ibase = t * 32;

        for (int i = 1; i < MPER; ++i) {
            float bv = -1.f; int bs = 0;
            #pragma unroll
            for (int s = 0; s < 32; ++s) {
                float dx = px[s] - cx, dy = py[s] - cy, dz = pz[s] - cz;
                float t0 = dx * dx, t1 = dy * dy, t2 = dz * dz;
                float d = (t0 + t1) + t2;
                float nd = fminf(dd[s], d);
                dd[s] = nd;
                bool bet = nd > bv;
                bv = bet ? nd : bv;
                bs = bet ? s : bs;
            }
            u64 key = ((u64)__float_as_uint(bv) << 32) | (u32)~(u32)(ibase + bs);

            DPP6(key);

            if (lane == 63) sm.red[i & 1][wv] = key;
            __syncthreads();

            const int p = i & 1;
            u64 k0 = sm.red[p][0], k1 = sm.red[p][1], k2 = sm.red[p][2], k3 = sm.red[p][3];
            u64 ka = k0 > k1 ? k0 : k1;
            u64 kb = k2 > k3 ? k2 : k3;
            u64 kbest = ka > kb ? ka : kb;
            const int i2 = (int)(~(u32)kbest) & 0x1FFF;

            float4 c = sm.spt[i2];
            cx = c.x; cy = c.y; cz = c.z;

            if (t == 0) {
                size_t row = (size_t)b * MPER + i;
                out_np[row*3+0] = cx; out_np[row*3+1] = cy; out_np[row*3+2] = cz;
                qpts[row] = make_float4(cx, cy, cz, 0.f);
                if (((i & 127) == 127) || (i >= 1536 && ((i & 31) == 31))) {
                    __threadfence();
                    __hip_atomic_store(prog + b * 32, (u32)(i + 1),
                                       __ATOMIC_RELEASE, __HIP_MEMORY_SCOPE_AGENT);
                }
            }
        }
    } else {
        // ============ KNN (R4-proven math), graded chunk sizes, gated on progress ============
        KnnSM& sm = *(KnnSM*)SMRAW;
        const int kb = blockIdx.x - NB;
        const int b  = kb / CPB;
        const int r  = kb % CPB;
        int nq, q0b;
        if (r < 24)      { nq = 64; q0b = r << 6; }
        else if (r < 32) { nq = 32; q0b = 1536 + ((r - 24) << 5); }
        else if (r < 40) { nq = 16; q0b = 1792 + ((r - 32) << 4); }
        else             { nq = 8;  q0b = 1920 + ((r - 40) << 3); }
        const int lgL = (nq == 64) ? 2 : (nq == 32) ? 3 : (nq == 16) ? 4 : 5;
        const int L = 1 << lgL;          // lanes per query
        const int lgP = 11 - lgL;
        const int P = 1 << lgP;          // points per lane per 2048-chunk
        const int stride = P + 2;        // float4 units; bank-offset 8 between subs
        const u32 need = (u32)(q0b + nq);

        // single-thread spin (de-stormed gate), then block-wide fence
        if (t == 0) {
            while (__hip_atomic_load(prog + b * 32, __ATOMIC_RELAXED,
                                     __HIP_MEMORY_SCOPE_AGENT) < need)
                __builtin_amdgcn_s_sleep(32);
        }
        __syncthreads();
        __threadfence();

        const int sub = t & (L - 1), qloc = t >> lgL;
        const int q = b * MPER + q0b + qloc;
        const float4 qp = qpts[q];
        const float qq = (qp.x * qp.x + qp.y * qp.y) + qp.z * qp.z;
        const float* pb = pts + (size_t)b * NPER * 3;
        const int wq = t >> 6, wl = t & 63;

        float4 Lr[6];
        #define LOADC(c) do { const float4* src_ = (const float4*)(pb + (size_t)(c) * 2048 * 3); \
            _Pragma("unroll") for (int u_ = 0; u_ < 6; ++u_) Lr[u_] = src_[t * 6 + u_]; } while (0)
        #define WRITEC(pbuf) do { \
            float fl_[24]; \
            _Pragma("unroll") for (int u_ = 0; u_ < 6; ++u_) { \
                fl_[u_*4+0]=Lr[u_].x; fl_[u_*4+1]=Lr[u_].y; fl_[u_*4+2]=Lr[u_].z; fl_[u_*4+3]=Lr[u_].w; } \
            _Pragma("unroll") for (int r_ = 0; r_ < 8; ++r_) { \
                float x_=fl_[3*r_], y_=fl_[3*r_+1], z_=fl_[3*r_+2]; \
                float pp_=(x_*x_ + y_*y_) + z_*z_; \
                int gpos_ = wq*512 + wl*8 + r_; \
                sm.sp[pbuf][(gpos_ >> lgP)*stride + (gpos_ & (P-1))] = make_float4(x_,y_,z_,pp_); } } while (0)

        // ---- pass 1: per-lane sorted top-16 distances over my P-pt sub-streams ----
        float nd[16];
        #pragma unroll
        for (int j = 0; j < 16; ++j) nd[j] = 1e30f;

        LOADC(0); WRITEC(0); LOADC(1);
        __syncthreads();
        for (int c = 0; c < 4; ++c) {
            const int pbuf = c & 1;
            const float4* rowp = &sm.sp[pbuf][sub * stride];
            #pragma unroll 4
            for (int j = 0; j < P; ++j) {
                float4 p = rowp[j];
                float dot = (qp.x * p.x + qp.y * p.y) + qp.z * p.z;
                float d = (qq + p.w) - 2.f * dot;
                if (d < nd[15]) {
                    #pragma unroll
                    for (int u = 15; u >= 1; --u) nd[u] = med3f(d, nd[u-1], nd[u]);
                    nd[0] = fminf(nd[0], d);
                }
            }
            __syncthreads();
            if (c < 3) {
                WRITEC((c + 1) & 1);
                if (c < 2) LOADC(c + 2);
                __syncthreads();
            }
        }
        #pragma unroll
        for (int j = 0; j < 16; ++j) sm.ndl[t][j] = nd[j];
        __syncthreads();

        // leader: exact 16th-smallest via med3-insertion over L sorted lists (early break)
        if (sub == 0) {
            float td[16];
            #pragma unroll
            for (int u = 0; u < 16; ++u) td[u] = 1e30f;
            for (int s = 0; s < L; ++s) {
                for (int u2 = 0; u2 < 16; ++u2) {
                    float v = sm.ndl[t + s][u2];
                    if (!(v < td[15])) break;     // row ascending -> rest can't insert
                    #pragma unroll
                    for (int u = 15; u >= 1; --u) td[u] = med3f(v, td[u-1], td[u]);
                    td[0] = fminf(td[0], v);
                }
            }
            sm.taub[qloc] = td[15];
        }
        __syncthreads();
        const float tau = sm.taub[qloc];

        // ---- pass 2: collect (d<tau) and (d==tau) separately (bit-identical recompute) ----
        int cnt = 0, ecn = 0;
        LOADC(0); WRITEC(0); LOADC(1);
        __syncthreads();
        for (int c = 0; c < 4; ++c) {
            const int pbuf = c & 1;
            const float4* rowp = &sm.sp[pbuf][sub * stride];
            for (int j = 0; j < P; ++j) {
                float4 p = rowp[j];
                float dot = (qp.x * p.x + qp.y * p.y) + qp.z * p.z;
                float d = (qq + p.w) - 2.f * dot;
                if (d <= tau) {
                    u32 pidx = (u32)(c * 2048 + (sub << lgP) + j);
                    if (d < tau) { if (cnt < 16) sm.candl[t][cnt++] = pidx; }
                    else         { if (ecn < 16) sm.eql[t][ecn++] = pidx; }
                }
            }
            __syncthreads();
            if (c < 3) {
                WRITEC((c + 1) & 1);
                if (c < 2) LOADC(c + 2);
                __syncthreads();
            }
        }
        sm.ccnt[t] = cnt; sm.ecnt[t] = ecn; sm.pcur[t] = 0;
        __syncthreads();

        // leader: output all <tau cands (order-free downstream), then ascending-index
        // quota fill from ==tau cands. Identical SET to reference top_k.
        if (sub == 0) {
            const int base = t;
            int kept = 0;
            size_t obase = (size_t)q * KNN;
            for (int s = 0; s < L; ++s) {
                int n = sm.ccnt[base + s];
                for (int e = 0; e < n && kept < 16; ++e)
                    nidx[obase + kept++] = b * NPER + (int)sm.candl[base + s][e];
            }
            while (kept < 16) {
                u32 best = 0xFFFFFFFFu; int bs = -1;
                for (int s = 0; s < L; ++s) {
                    u32 ps = sm.pcur[base + s];
                    u32 v = (ps < (u32)sm.ecnt[base + s]) ? sm.eql[base + s][ps] : 0xFFFFFFFFu;
                    if (v < best) { best = v; bs = s; }
                }
                if (bs < 0) break;
                sm.pcur[base + bs]++;
                nidx[obase + kept++] = b * NPER + (int)best;
            }
        }
        #undef LOADC
        #undef WRITEC
    }
}

// ---------------- fused gather + linear + stats + k-minmax ----------------
__launch_bounds__(128, 4)
__global__ void k_stats(const float* __restrict__ pts, const float* __restrict__ feat,
                        const float* __restrict__ W, const int* __restrict__ nidx,
                        const float4* __restrict__ qpts, float* __restrict__ ymax,
                        float* __restrict__ ymin, float* __restrict__ stats) {
    __shared__ float4 g4[KNN][17];
    const int t = threadIdx.x;
    float w[68];
    const float* wr = W + t * 67;
    #pragma unroll
    for (int c = 0; c < 64; ++c) w[c] = wr[3 + c];
    w[64] = wr[0]; w[65] = wr[1]; w[66] = wr[2]; w[67] = 0.f;

    float s_sum = 0.f, s_sq = 0.f;
    const int k0 = t >> 3, p8 = t & 7;
    for (int mi = 0; mi < 8; ++mi) {
        const int m0 = blockIdx.x * 8 + mi;
        {
            int nid = nidx[(size_t)m0 * KNN + k0];
            const float4* fr = (const float4*)(feat + (size_t)nid * CIN);
            g4[k0][p8*2]   = fr[p8*2];
            g4[k0][p8*2+1] = fr[p8*2+1];
        }
        if (t < 16) {
            int nid = nidx[(size_t)m0 * KNN + t];
            float4 qp = qpts[m0];
            float x = pts[(size_t)nid*3], y = pts[(size_t)nid*3+1], z = pts[(size_t)nid*3+2];
            g4[t][16] = make_float4(x - qp.x, y - qp.y, z - qp.z, 0.f);
        }
        __syncthreads();
        float vmax = -1e30f, vmin = 1e30f;
        #pragma unroll 1
        for (int k = 0; k < KNN; ++k) {
            float y0 = 0.f, y1 = 0.f, y2 = 0.f, y3 = 0.f;
            #pragma unroll
            for (int c4 = 0; c4 < 17; ++c4) {
                float4 gv = g4[k][c4];
                y0 = fmaf(gv.x, w[c4*4+0], y0);
                y1 = fmaf(gv.y, w[c4*4+1], y1);
                y2 = fmaf(gv.z, w[c4*4+2], y2);
                y3 = fmaf(gv.w, w[c4*4+3], y3);
            }
            float y = (y0 + y1) + (y2 + y3);
            vmax = fmaxf(vmax, y); vmin = fminf(vmin, y);
            s_sum += y; s_sq = fmaf(y, y, s_sq);
        }
        ymax[(size_t)m0 * CO + t] = vmax;
        ymin[(size_t)m0 * CO + t] = vmin;
        __syncthreads();
    }
    atomicAdd(stats + t, s_sum);
    atomicAdd(stats + CO + t, s_sq);
}

// ---------------- epilogue: BN finalize (inlined) + relu(s*ext + b) ----------------
__global__ void k_out(const float* __restrict__ ymax, const float* __restrict__ ymin,
                      const float* __restrict__ stats, const float* __restrict__ gamma,
                      const float* __restrict__ beta, float* __restrict__ out_feat) {
    int tid = blockIdx.x * 256 + threadIdx.x;
    int o = tid & (CO - 1);
    const float inv = 1.f / (float)(MTOT * KNN);
    float mean = stats[o] * inv;
    float var = stats[CO + o] * inv - mean * mean;
    var = fmaxf(var, 0.f);
    float s = gamma[o] * rsqrtf(var + 1e-5f);
    float bb = beta[o] - mean * s;
    float yv = (s >= 0.f) ? ymax[tid] : ymin[tid];
    out_feat[tid] = fmaxf(fmaf(s, yv, bb), 0.f);
}

extern "C" void kernel_launch(void* const* d_in, const int* in_sizes, int n_in,
                              void* d_out, int out_size, void* d_ws, size_t ws_size,
                              hipStream_t stream) {
    const float* pts   = (const float*)d_in[0];
    const float* feat  = (const float*)d_in[1];
    const float* W     = (const float*)d_in[3];
    const float* gamma = (const float*)d_in[4];
    const float* beta  = (const float*)d_in[5];
    float* out = (float*)d_out;
    char* ws = (char*)d_ws;

    float4* qpts = (float4*)(ws);                       // 131072 B
    int*    nidx = (int*)(ws + 131072);                 // 524288 B
    float*  stats = (float*)(ws + 655360);              // 1024 B
    u32*    prog  = (u32*)(ws + 656384);                // 512 B (4 batches x 128B apart)
    float*  ymax  = (float*)(ws + 657408);              // 4 MB
    float*  ymin  = (float*)(ws + 657408 + 4194304);    // 4 MB

    float* out_np   = out;                    // (8192,3)
    float* out_feat = out + 24576;            // (8192,128)
    float* out_rs   = out + 24576 + 1048576;  // (5,)

    hipLaunchKernelGGL(k_init,  dim3(1), dim3(256), 0, stream, stats, out_rs, prog);
    hipLaunchKernelGGL(k_mega,  dim3(NB + NB * CPB), dim3(256), 0, stream,
                       pts, out_np, qpts, prog, nidx);
    hipLaunchKernelGGL(k_stats, dim3(MTOT / 8), dim3(128), 0, stream,
                       pts, feat, W, nidx, qpts, ymax, ymin, stats);
    hipLaunchKernelGGL(k_out,   dim3(MTOT * CO / 256), dim3(256), 0, stream,
                       ymax, ymin, stats, gamma, beta, out_feat);
}

// Round 10
// 2020.518 us; speedup vs baseline: 2.1139x; 1.0171x over previous
//
#include <hip/hip_runtime.h>

#define NB 4
#define NPER 8192
#define MPER 2048
#define KNN 16
#define CIN 64
#define CO 128
#define MTOT (NB*MPER)
#define CPB 56          // knn chunks per batch: 24x64q + 8x32q + 8x16q + 16x8q

typedef unsigned long long u64;
typedef unsigned int u32;

__device__ __forceinline__ float med3f(float a, float b, float c) {
    return __builtin_amdgcn_fmed3f(a, b, c);
}

// ---------------- init: zero stats + progress, write row_splits ----------------
__global__ void k_init(float* __restrict__ stats, float* __restrict__ rs,
                       u32* __restrict__ prog) {
    int t = threadIdx.x;
    if (t < 256) stats[t] = 0.f;
    if (t < 128) prog[t] = 0u;
    if (t < 5) rs[t] = (float)(t * MPER);
}

// DPP compare-select step on a packed u64 key (max).
#define DPPSTEP(key, CTRL, RM) do {                                                   \
    unsigned lo_ = (unsigned)(key), hi_ = (unsigned)((key) >> 32);                    \
    unsigned nlo = (unsigned)__builtin_amdgcn_update_dpp((int)lo_, (int)lo_, CTRL, RM, 0xf, false); \
    unsigned nhi = (unsigned)__builtin_amdgcn_update_dpp((int)hi_, (int)hi_, CTRL, RM, 0xf, false); \
    unsigned long long ok_ = ((unsigned long long)nhi << 32) | nlo;                   \
    if (ok_ > (key)) (key) = ok_;                                                     \
} while (0)

#define DPP6(key) do { \
    DPPSTEP(key, 0xB1,  0xF); \
    DPPSTEP(key, 0x4E,  0xF); \
    DPPSTEP(key, 0x141, 0xF); \
    DPPSTEP(key, 0x140, 0xF); \
    DPPSTEP(key, 0x142, 0xA); \
    DPPSTEP(key, 0x143, 0xC); \
} while (0)

// ---------------- megakernel: blocks 0-3 = FPS, blocks 4-227 = KNN+stats ----------------
struct FpsSM {
    float4 spt[NPER];          // 128 KiB point table
    u64 red[2][4];             // parity-double-buffered wave partials
};
struct KnnSM {
    float4 sp[2][2112];        // staged chunk, per-sub stride P+2 (bank-safe)
    float  ndl[256][16];
    u32    candl[256][16];     // d < tau candidates (globally <= 15)
    u32    eql[256][16];       // d == tau candidates
    int    ccnt[256], ecnt[256];
    u32    pcur[256];
    float  taub[64];
    u32    nidxL[64][16];      // merged neighbor ids (global point ids)
    float4 g4[2][16][18];      // gather staging for stats (double-buffered)
};
#define SMBYTES (sizeof(FpsSM) > sizeof(KnnSM) ? sizeof(FpsSM) : sizeof(KnnSM))

__launch_bounds__(256, 1)
__global__ void k_mega(const float* __restrict__ pts, const float* __restrict__ feat,
                       const float* __restrict__ W, float* __restrict__ out_np,
                       float4* __restrict__ qpts, u32* __restrict__ prog,
                       float* __restrict__ ymax, float* __restrict__ ymin,
                       float* __restrict__ stats) {
    #pragma clang fp contract(off)
    __shared__ __align__(16) char SMRAW[SMBYTES];
    const int t = threadIdx.x;

    if (blockIdx.x < NB) {
        // ================= FPS (R2-proven body, 256 thr, 32 pts/lane) =================
        FpsSM& sm = *(FpsSM*)SMRAW;
        const int b = blockIdx.x;
        const float4* pb4 = (const float4*)(pts + (size_t)b * NPER * 3);

        float f[96];
        #pragma unroll
        for (int j = 0; j < 24; ++j) {
            float4 v = pb4[t * 24 + j];
            f[j*4+0] = v.x; f[j*4+1] = v.y; f[j*4+2] = v.z; f[j*4+3] = v.w;
        }
        float px[32], py[32], pz[32], dd[32];
        #pragma unroll
        for (int s = 0; s < 32; ++s) {
            px[s] = f[3*s]; py[s] = f[3*s+1]; pz[s] = f[3*s+2];
            dd[s] = 1e10f;
            sm.spt[t * 32 + s] = make_float4(px[s], py[s], pz[s], 0.f);
        }
        if (t == 0) {
            size_t row = (size_t)b * MPER;
            out_np[row*3+0] = px[0]; out_np[row*3+1] = py[0]; out_np[row*3+2] = pz[0];
            qpts[row] = make_float4(px[0], py[0], pz[0], 0.f);
        }
        __syncthreads();

        float4 c0 = sm.spt[0];
        float cx = c0.x, cy = c0.y, cz = c0.z;
        const int lane = t & 63, wv = t >> 6;
        const int ibase = t * 32;

        for (int i = 1; i < MPER; ++i) {
            float bv = -1.f; int bs = 0;
            #pragma unroll
            for (int s = 0; s < 32; ++s) {
                float dx = px[s] - cx, dy = py[s] - cy, dz = pz[s] - cz;
                float t0 = dx * dx, t1 = dy * dy, t2 = dz * dz;
                float d = (t0 + t1) + t2;
                float nd = fminf(dd[s], d);
                dd[s] = nd;
                bool bet = nd > bv;
                bv = bet ? nd : bv;
                bs = bet ? s : bs;
            }
            u64 key = ((u64)__float_as_uint(bv) << 32) | (u32)~(u32)(ibase + bs);

            DPP6(key);

            if (lane == 63) sm.red[i & 1][wv] = key;
            __syncthreads();

            // publisher on wave 1: all waves' global stores (rows <= i-1) were drained
            // by the barrier's vmcnt(0); release store does the L2 writeback.
            if (t == 64 && (((i & 127) == 0) || (i >= 1536 && (i & 31) == 0))) {
                __hip_atomic_store(prog + b * 32, (u32)i,
                                   __ATOMIC_RELEASE, __HIP_MEMORY_SCOPE_AGENT);
            }

            const int p = i & 1;
            u64 k0 = sm.red[p][0], k1 = sm.red[p][1], k2 = sm.red[p][2], k3 = sm.red[p][3];
            u64 ka = k0 > k1 ? k0 : k1;
            u64 kb = k2 > k3 ? k2 : k3;
            u64 kbest = ka > kb ? ka : kb;
            const int i2 = (int)(~(u32)kbest) & 0x1FFF;

            float4 c = sm.spt[i2];
            cx = c.x; cy = c.y; cz = c.z;

            if (t == 0) {
                size_t row = (size_t)b * MPER + i;
                out_np[row*3+0] = cx; out_np[row*3+1] = cy; out_np[row*3+2] = cz;
                qpts[row] = make_float4(cx, cy, cz, 0.f);
            }
        }
        __syncthreads();   // drains the final row's stores (vmcnt(0) per wave)
        if (t == 64) {
            __hip_atomic_store(prog + b * 32, (u32)MPER,
                               __ATOMIC_RELEASE, __HIP_MEMORY_SCOPE_AGENT);
        }
    } else {
        // ============ KNN (R9-proven math) + folded stats, gated on progress ============
        KnnSM& sm = *(KnnSM*)SMRAW;
        const int kb = blockIdx.x - NB;
        const int b  = kb / CPB;
        const int r  = kb % CPB;
        int nq, q0b;
        if (r < 24)      { nq = 64; q0b = r << 6; }
        else if (r < 32) { nq = 32; q0b = 1536 + ((r - 24) << 5); }
        else if (r < 40) { nq = 16; q0b = 1792 + ((r - 32) << 4); }
        else             { nq = 8;  q0b = 1920 + ((r - 40) << 3); }
        const int lgL = (nq == 64) ? 2 : (nq == 32) ? 3 : (nq == 16) ? 4 : 5;
        const int L = 1 << lgL;          // lanes per query
        const int lgP = 11 - lgL;
        const int P = 1 << lgP;          // points per lane per 2048-chunk
        const int stride = P + 2;        // float4 units; bank-offset 8 between subs
        const u32 need = (u32)(q0b + nq);

        // single-thread spin (de-stormed gate), then block-wide fence
        if (t == 0) {
            while (__hip_atomic_load(prog + b * 32, __ATOMIC_RELAXED,
                                     __HIP_MEMORY_SCOPE_AGENT) < need)
                __builtin_amdgcn_s_sleep(32);
        }
        __syncthreads();
        __threadfence();

        const int sub = t & (L - 1), qloc = t >> lgL;
        const int q = b * MPER + q0b + qloc;
        const float4 qp = qpts[q];
        const float qq = (qp.x * qp.x + qp.y * qp.y) + qp.z * qp.z;
        const float* pb = pts + (size_t)b * NPER * 3;
        const int wq = t >> 6, wl = t & 63;

        float4 Lr[6];
        #define LOADC(c) do { const float4* src_ = (const float4*)(pb + (size_t)(c) * 2048 * 3); \
            _Pragma("unroll") for (int u_ = 0; u_ < 6; ++u_) Lr[u_] = src_[t * 6 + u_]; } while (0)
        #define WRITEC(pbuf) do { \
            float fl_[24]; \
            _Pragma("unroll") for (int u_ = 0; u_ < 6; ++u_) { \
                fl_[u_*4+0]=Lr[u_].x; fl_[u_*4+1]=Lr[u_].y; fl_[u_*4+2]=Lr[u_].z; fl_[u_*4+3]=Lr[u_].w; } \
            _Pragma("unroll") for (int r_ = 0; r_ < 8; ++r_) { \
                float x_=fl_[3*r_], y_=fl_[3*r_+1], z_=fl_[3*r_+2]; \
                float pp_=(x_*x_ + y_*y_) + z_*z_; \
                int gpos_ = wq*512 + wl*8 + r_; \
                sm.sp[pbuf][(gpos_ >> lgP)*stride + (gpos_ & (P-1))] = make_float4(x_,y_,z_,pp_); } } while (0)

        // ---- pass 1: per-lane sorted top-16 distances over my P-pt sub-streams ----
        float nd[16];
        #pragma unroll
        for (int j = 0; j < 16; ++j) nd[j] = 1e30f;

        LOADC(0); WRITEC(0); LOADC(1);
        __syncthreads();
        for (int c = 0; c < 4; ++c) {
            const int pbuf = c & 1;
            const float4* rowp = &sm.sp[pbuf][sub * stride];
            #pragma unroll 4
            for (int j = 0; j < P; ++j) {
                float4 p = rowp[j];
                float dot = (qp.x * p.x + qp.y * p.y) + qp.z * p.z;
                float d = (qq + p.w) - 2.f * dot;
                if (d < nd[15]) {
                    #pragma unroll
                    for (int u = 15; u >= 1; --u) nd[u] = med3f(d, nd[u-1], nd[u]);
                    nd[0] = fminf(nd[0], d);
                }
            }
            __syncthreads();
            if (c < 3) {
                WRITEC((c + 1) & 1);
                if (c < 2) LOADC(c + 2);
                __syncthreads();
            }
        }
        #pragma unroll
        for (int j = 0; j < 16; ++j) sm.ndl[t][j] = nd[j];
        __syncthreads();

        // leader: exact 16th-smallest via med3-insertion over L sorted lists (early break)
        if (sub == 0) {
            float td[16];
            #pragma unroll
            for (int u = 0; u < 16; ++u) td[u] = 1e30f;
            for (int s = 0; s < L; ++s) {
                for (int u2 = 0; u2 < 16; ++u2) {
                    float v = sm.ndl[t + s][u2];
                    if (!(v < td[15])) break;     // row ascending -> rest can't insert
                    #pragma unroll
                    for (int u = 15; u >= 1; --u) td[u] = med3f(v, td[u-1], td[u]);
                    td[0] = fminf(td[0], v);
                }
            }
            sm.taub[qloc] = td[15];
        }
        __syncthreads();
        const float tau = sm.taub[qloc];

        // ---- pass 2: collect (d<tau) and (d==tau) separately (bit-identical recompute) ----
        int cnt = 0, ecn = 0;
        LOADC(0); WRITEC(0); LOADC(1);
        __syncthreads();
        for (int c = 0; c < 4; ++c) {
            const int pbuf = c & 1;
            const float4* rowp = &sm.sp[pbuf][sub * stride];
            for (int j = 0; j < P; ++j) {
                float4 p = rowp[j];
                float dot = (qp.x * p.x + qp.y * p.y) + qp.z * p.z;
                float d = (qq + p.w) - 2.f * dot;
                if (d <= tau) {
                    u32 pidx = (u32)(c * 2048 + (sub << lgP) + j);
                    if (d < tau) { if (cnt < 16) sm.candl[t][cnt++] = pidx; }
                    else         { if (ecn < 16) sm.eql[t][ecn++] = pidx; }
                }
            }
            __syncthreads();
            if (c < 3) {
                WRITEC((c + 1) & 1);
                if (c < 2) LOADC(c + 2);
                __syncthreads();
            }
        }
        sm.ccnt[t] = cnt; sm.ecnt[t] = ecn; sm.pcur[t] = 0;
        __syncthreads();

        // leader: all <tau cands (order-free downstream), then ascending-index quota
        // fill from ==tau cands. Identical SET to reference top_k. Stash in LDS.
        if (sub == 0) {
            const int base = t;
            int kept = 0;
            for (int s = 0; s < L; ++s) {
                int n = sm.ccnt[base + s];
                for (int e = 0; e < n && kept < 16; ++e)
                    sm.nidxL[qloc][kept++] = (u32)(b * NPER) + sm.candl[base + s][e];
            }
            while (kept < 16) {
                u32 best = 0xFFFFFFFFu; int bs = -1;
                for (int s = 0; s < L; ++s) {
                    u32 ps = sm.pcur[base + s];
                    u32 v = (ps < (u32)sm.ecnt[base + s]) ? sm.eql[base + s][ps] : 0xFFFFFFFFu;
                    if (v < best) { best = v; bs = s; }
                }
                if (bs < 0) break;
                sm.pcur[base + bs]++;
                sm.nidxL[qloc][kept++] = (u32)(b * NPER) + best;
            }
        }
        __syncthreads();

        // ---- folded stats phase: thread = (channel o = t>>1, k-half kh = t&1) ----
        const int o = t >> 1, kh = t & 1;
        float w[68];
        {
            const float* wr = W + o * 67;
            #pragma unroll
            for (int c = 0; c < 64; ++c) w[c] = wr[3 + c];
            w[64] = wr[0]; w[65] = wr[1]; w[66] = wr[2]; w[67] = 0.f;
        }
        const int gn = t >> 4, gf = t & 15;   // gather: neighbor, float4-slot
        float ssum = 0.f, ssq = 0.f;

        float4 gfv, gxv = make_float4(0.f, 0.f, 0.f, 0.f);
        {
            int nid = (int)sm.nidxL[0][gn];
            gfv = ((const float4*)(feat + (size_t)nid * CIN))[gf];
            if (t < 16) {
                int nid2 = (int)sm.nidxL[0][t];
                float4 qp2 = qpts[(size_t)b * MPER + q0b];
                gxv = make_float4(pts[(size_t)nid2*3]   - qp2.x,
                                  pts[(size_t)nid2*3+1] - qp2.y,
                                  pts[(size_t)nid2*3+2] - qp2.z, 0.f);
            }
        }
        for (int mi = 0; mi < nq; ++mi) {
            const int buf = mi & 1;
            sm.g4[buf][gn][gf] = gfv;
            if (t < 16) sm.g4[buf][t][16] = gxv;
            if (mi + 1 < nq) {
                int nid = (int)sm.nidxL[mi+1][gn];
                gfv = ((const float4*)(feat + (size_t)nid * CIN))[gf];
                if (t < 16) {
                    int nid2 = (int)sm.nidxL[mi+1][t];
                    float4 qp2 = qpts[(size_t)b * MPER + q0b + mi + 1];
                    gxv = make_float4(pts[(size_t)nid2*3]   - qp2.x,
                                      pts[(size_t)nid2*3+1] - qp2.y,
                                      pts[(size_t)nid2*3+2] - qp2.z, 0.f);
                }
            }
            __syncthreads();
            float vmax = -1e30f, vmin = 1e30f;
            #pragma unroll 1
            for (int kk = 0; kk < 8; ++kk) {
                const int k = kh * 8 + kk;
                float y0 = 0.f, y1 = 0.f, y2 = 0.f, y3 = 0.f;
                #pragma unroll
                for (int c4 = 0; c4 < 17; ++c4) {
                    float4 gv = sm.g4[buf][k][c4];
                    y0 = fmaf(gv.x, w[c4*4+0], y0);
                    y1 = fmaf(gv.y, w[c4*4+1], y1);
                    y2 = fmaf(gv.z, w[c4*4+2], y2);
                    y3 = fmaf(gv.w, w[c4*4+3], y3);
                }
                float y = (y0 + y1) + (y2 + y3);
                vmax = fmaxf(vmax, y); vmin = fminf(vmin, y);
                ssum += y; ssq = fmaf(y, y, ssq);
            }
            float vM = fmaxf(vmax, __shfl_xor(vmax, 1));
            float vm = fminf(vmin, __shfl_xor(vmin, 1));
            if (kh == 0) {
                size_t mrow = (size_t)(b * MPER + q0b + mi) * CO + o;
                ymax[mrow] = vM; ymin[mrow] = vm;
            }
        }
        float ts = ssum + __shfl_xor(ssum, 1);
        float tq = ssq  + __shfl_xor(ssq, 1);
        if (kh == 0) {
            atomicAdd(stats + o, ts);
            atomicAdd(stats + CO + o, tq);
        }
        #undef LOADC
        #undef WRITEC
    }
}

// ---------------- epilogue: BN finalize (inlined) + relu(s*ext + b) ----------------
__global__ void k_out(const float* __restrict__ ymax, const float* __restrict__ ymin,
                      const float* __restrict__ stats, const float* __restrict__ gamma,
                      const float* __restrict__ beta, float* __restrict__ out_feat) {
    int tid = blockIdx.x * 256 + threadIdx.x;
    int o = tid & (CO - 1);
    const float inv = 1.f / (float)(MTOT * KNN);
    float mean = stats[o] * inv;
    float var = stats[CO + o] * inv - mean * mean;
    var = fmaxf(var, 0.f);
    float s = gamma[o] * rsqrtf(var + 1e-5f);
    float bb = beta[o] - mean * s;
    float yv = (s >= 0.f) ? ymax[tid] : ymin[tid];
    out_feat[tid] = fmaxf(fmaf(s, yv, bb), 0.f);
}

extern "C" void kernel_launch(void* const* d_in, const int* in_sizes, int n_in,
                              void* d_out, int out_size, void* d_ws, size_t ws_size,
                              hipStream_t stream) {
    const float* pts   = (const float*)d_in[0];
    const float* feat  = (const float*)d_in[1];
    const float* W     = (const float*)d_in[3];
    const float* gamma = (const float*)d_in[4];
    const float* beta  = (const float*)d_in[5];
    float* out = (float*)d_out;
    char* ws = (char*)d_ws;

    float4* qpts = (float4*)(ws);                       // 131072 B
    float*  stats = (float*)(ws + 655360);              // 1024 B
    u32*    prog  = (u32*)(ws + 656384);                // 512 B (4 batches x 128B apart)
    float*  ymax  = (float*)(ws + 657408);              // 4 MB
    float*  ymin  = (float*)(ws + 657408 + 4194304);    // 4 MB

    float* out_np   = out;                    // (8192,3)
    float* out_feat = out + 24576;            // (8192,128)
    float* out_rs   = out + 24576 + 1048576;  // (5,)

    hipLaunchKernelGGL(k_init,  dim3(1), dim3(256), 0, stream, stats, out_rs, prog);
    hipLaunchKernelGGL(k_mega,  dim3(NB + NB * CPB), dim3(256), 0, stream,
                       pts, feat, W, out_np, qpts, prog, ymax, ymin, stats);
    hipLaunchKernelGGL(k_out,   dim3(MTOT * CO / 256), dim3(256), 0, stream,
                       ymax, ymin, stats, gamma, beta, out_feat);
}